// Round 8
// baseline (5594.624 us; speedup 1.0000x reference)
//
#include <hip/hip_runtime.h>
#include <math.h>

#define B 512
#define S 64
#define T 32
#define E 512
#define H 1024
#define VOUTD 128
#define H2 (2*H)
#define H3 (3*H)
#define H6 (6*H)

typedef unsigned short ushortT;
typedef unsigned int uintT;
typedef __attribute__((ext_vector_type(8))) short short8;
typedef __attribute__((ext_vector_type(4))) float floatx4;

__device__ __forceinline__ float sigmoidf_(float x) { return 1.0f / (1.0f + expf(-x)); }

__device__ __forceinline__ uintT pack_hi2(float a, float b) {
    return (__float_as_uint(a) >> 16) | (__float_as_uint(b) & 0xFFFF0000u);
}
__device__ __forceinline__ uintT pack_lo2(float a, float b) {
    uintT ua = __float_as_uint(a), ub = __float_as_uint(b);
    uintT la = __float_as_uint(a - __uint_as_float(ua & 0xFFFF0000u)) >> 16;
    uintT lb = __float_as_uint(b - __uint_as_float(ub & 0xFFFF0000u)) >> 16;
    return la | (lb << 16);
}

__global__ __launch_bounds__(256) void zero16(uint4* __restrict__ p, int n)
{
    int i = blockIdx.x * 256 + threadIdx.x;
    if (i < n) p[i] = make_uint4(0u, 0u, 0u, 0u);
}

// ===========================================================================
// W -> fragment-major hi/lo planes. COALESCED: one wave per fragment.
// Fragment f = (jb*ncK + c)*3 + g; 1024 shorts (hi 512 | lo 512).
// Lane l: jl=l&15, kq=l>>4 reads W[g*nj + jb*16 + jl][c*32 + kq*8 .. +8)
// and writes out[f*1024 + l*8] (hi) and +512 (lo): contiguous 1KB per wave.
// ncK = K/32 = 1 << (kShift-2)  =>  jb = rest >> (kShift-2).
// ===========================================================================
__global__ __launch_bounds__(256) void swizzle_w(
    const float* __restrict__ W, ushortT* __restrict__ out, int njShift, int kShift)
{
    const int K = 8 << kShift;
    const int nj = 1 << njShift;
    const int ncK = K >> 5;
    const int total = (nj >> 4) * ncK * 3;
    int f = blockIdx.x * 4 + (threadIdx.x >> 6);
    if (f >= total) return;
    const int lane = threadIdx.x & 63;
    int g = f % 3;
    int rest = f / 3;
    int c = rest & (ncK - 1);
    int jb = rest >> (kShift - 2);
    int jl = lane & 15, kq = lane >> 4;
    int row = g * nj + jb * 16 + jl;
    int k = c * 32 + kq * 8;
    const float* s = W + (size_t)row * K + k;
    float4 f0 = *(const float4*)s;
    float4 f1 = *(const float4*)(s + 4);
    uint4 hv = make_uint4(pack_hi2(f0.x, f0.y), pack_hi2(f0.z, f0.w),
                          pack_hi2(f1.x, f1.y), pack_hi2(f1.z, f1.w));
    uint4 lv = make_uint4(pack_lo2(f0.x, f0.y), pack_lo2(f0.z, f0.w),
                          pack_lo2(f1.x, f1.y), pack_lo2(f1.z, f1.w));
    size_t base = (size_t)f * 1024 + (size_t)lane * 8;
    *(uint4*)(out + base) = hv;
    *(uint4*)(out + base + 512) = lv;
}

// ===========================================================================
// Barrier-free streaming main loop, 4-DEEP register pipeline: each wave
// reads ITS OWN B fragments (jb-half = wc) and A row-frags (wr) straight
// global->register, prefetched 3 chunk-slots (~400cy) ahead of use. No LDS,
// no __syncthreads in the loop; compiler emits counted vmcnt per use.
// MFMA order per acc: Ah*Bh, Ah*Bl, Al*Bh; chunks ascending (bit-identical
// numerics to R3..R7).
// ===========================================================================
#define MFMA16(a, b, c) __builtin_amdgcn_mfma_f32_16x16x32_bf16(a, b, c, 0, 0, 0)

#define LOADSET(SET, C)                                                         \
    {                                                                           \
        const ushortT* bp_ = bPtr + (size_t)(C) * 3072;                         \
        SET##b[0] = *(const short8*)(bp_);                                      \
        SET##b[1] = *(const short8*)(bp_ + 512);                                \
        SET##b[2] = *(const short8*)(bp_ + 1024);                               \
        SET##b[3] = *(const short8*)(bp_ + 1536);                               \
        SET##b[4] = *(const short8*)(bp_ + 2048);                               \
        SET##b[5] = *(const short8*)(bp_ + 2560);                               \
        const ushortT* ap_ = aPtr + (size_t)(C) * 1024;                         \
        SET##a[0] = *(const short8*)(ap_);                                      \
        SET##a[1] = *(const short8*)(ap_ + 512);                                \
        SET##a[2] = *(const short8*)(ap_ + NCKd * 1024);                        \
        SET##a[3] = *(const short8*)(ap_ + NCKd * 1024 + 512);                  \
    }

#define COMPSET(SET)                                                            \
    _Pragma("unroll")                                                           \
    for (int g = 0; g < 3; ++g) {                                               \
        short8 bh_ = SET##b[g * 2], bl_ = SET##b[g * 2 + 1];                    \
        acc[0][g] = MFMA16(SET##a[0], bh_, acc[0][g]);                          \
        acc[0][g] = MFMA16(SET##a[0], bl_, acc[0][g]);                          \
        acc[0][g] = MFMA16(SET##a[1], bh_, acc[0][g]);                          \
        acc[1][g] = MFMA16(SET##a[2], bh_, acc[1][g]);                          \
        acc[1][g] = MFMA16(SET##a[2], bl_, acc[1][g]);                          \
        acc[1][g] = MFMA16(SET##a[3], bh_, acc[1][g]);                          \
    }

#define MAIN_LOOP()                                                             \
    LOADSET(s0, 0);                                                             \
    LOADSET(s1, 1);                                                             \
    LOADSET(s2, 2);                                                             \
    for (int c = 0; c < NCKd; c += 4) {                                         \
        LOADSET(s3, c + 3);                                                     \
        COMPSET(s0);                                                            \
        if (c + 4 < NCKd) LOADSET(s0, c + 4);                                   \
        COMPSET(s1);                                                            \
        if (c + 5 < NCKd) LOADSET(s1, c + 5);                                   \
        COMPSET(s2);                                                            \
        if (c + 6 < NCKd) LOADSET(s2, c + 6);                                   \
        COMPSET(s3);                                                            \
    }

// Coalesced fragment-plane epilogue: stage packed shorts in LDS, one
// barrier, stream out 8KB contiguous (2 uint4/thread).
#define EPILOGUE_STORE(NCKA)                                                    \
    __syncthreads();                                                            \
    _Pragma("unroll")                                                           \
    for (int v = 0; v < 2; ++v) {                                               \
        int idx = t * 2 + v;                                                    \
        int rbo = idx >> 7;                                                     \
        int offs = (idx & 127) * 8;                                             \
        size_t gbase = ((size_t)((m0 >> 4) + rbo) * (NCKA) + cA) * 1024;        \
        *(uint4*)(AfrOut + gbase + offs) = *(const uint4*)&eb[rbo * 1024 + offs]; \
    }

// ===========================================================================
// FUSED encoder step. Block: 64 rows x 32 j, 4 waves (2x2). Barrier-free.
// ===========================================================================
__global__ __launch_bounds__(256, 2) void fused_step_enc(
    const ushortT* __restrict__ Afr,
    const ushortT* __restrict__ WfrF, const ushortT* __restrict__ WfrB,
    const float* __restrict__ giTabF, const float* __restrict__ giTabB,
    const int* __restrict__ src, int s,
    const float* __restrict__ bhF, const float* __restrict__ bhB,
    float* __restrict__ h, ushortT* __restrict__ AfrOut)
{
    __shared__ ushortT eb[4096];          // 8 KB epilogue staging
    const int t = threadIdx.x, lane = t & 63, w = t >> 6;
    const int bid = blockIdx.x;
    const int xcd = bid & 7, q = bid >> 3;
    const int jg = xcd + 8 * (q & 3);     // [0,32)
    const int mb = q >> 2;                // [0,16)
    const int j0 = jg * 32, m0 = mb * 64;
    const bool bwd = (m0 >= B);
    const ushortT* Wfr = bwd ? WfrB : WfrF;
    const float* giTab = bwd ? giTabB : giTabF;
    const float* bh = bwd ? bhB : bhF;
    const int NCKd = 32;
    const int sidx = bwd ? (S - 1 - s) : s;

    const int wr = w >> 1, wc = w & 1;
    const ushortT* aPtr = Afr + (size_t)((m0 >> 4) + wr * 2) * (NCKd * 1024) + lane * 8;
    const ushortT* bPtr = Wfr + (size_t)(jg * 2 + wc) * (NCKd * 3072) + lane * 8;

    floatx4 acc[2][3];
#pragma unroll
    for (int mi = 0; mi < 2; ++mi)
#pragma unroll
        for (int g = 0; g < 3; ++g) acc[mi][g] = (floatx4){0.f, 0.f, 0.f, 0.f};

    short8 s0b[6], s0a[4], s1b[6], s1a[4], s2b[6], s2a[4], s3b[6], s3a[4];
    MAIN_LOOP();

    // fused gate epilogue: h fp32 RMW + packed bf16 planes staged to LDS.
    const int colj = j0 + wc * 16 + (lane & 15);
    const float bR = bh[colj], bZ = bh[H + colj], bN = bh[2 * H + colj];
    const int rloc0 = wr * 32 + (lane >> 4) * 4;
    const int cA = j0 >> 5;
    const int innerB = ((colj >> 3) & 3) * 128 + (colj & 7);
#pragma unroll
    for (int mi = 0; mi < 2; ++mi) {
#pragma unroll
        for (int r = 0; r < 4; ++r) {
            const int rloc = rloc0 + mi * 16 + r;
            const int row = m0 + rloc;
            const int tk = src[(row & (B - 1)) * S + sidx];
            const float* gi = giTab + (size_t)tk * H3;
            float ghr = acc[mi][0][r] + bR;
            float ghz = acc[mi][1][r] + bZ;
            float ghn = acc[mi][2][r] + bN;
            float rr = sigmoidf_(gi[colj] + ghr);
            float z  = sigmoidf_(gi[H + colj] + ghz);
            float n  = tanhf(gi[2 * H + colj] + rr * ghn);
            const size_t idx = (size_t)row * H + colj;
            float hnew = (1.0f - z) * n + z * h[idx];
            h[idx] = hnew;
            uintT u = __float_as_uint(hnew);
            const int rbl = wr * 2 + mi;
            const int inner = ((lane >> 4) * 4 + r) * 8 + innerB;
            eb[rbl * 1024 + inner] = (ushortT)(u >> 16);
            eb[rbl * 1024 + 512 + inner] =
                (ushortT)(__float_as_uint(hnew - __uint_as_float(u & 0xFFFF0000u)) >> 16);
        }
    }
    EPILOGUE_STORE(32)
}

// ===========================================================================
// FUSED decoder step: Hd = 2H, gates {j, 2H+j, 4H+j}. Barrier-free.
// ===========================================================================
__global__ __launch_bounds__(256, 2) void fused_step_dec(
    const ushortT* __restrict__ Afr, const ushortT* __restrict__ Wfr,
    const float* __restrict__ giTabD, const int* __restrict__ tok,
    const float* __restrict__ bhD,
    float* __restrict__ h, ushortT* __restrict__ AfrOut)
{
    __shared__ ushortT eb[4096];
    const int t = threadIdx.x, lane = t & 63, w = t >> 6;
    const int bid = blockIdx.x;
    const int xcd = bid & 7, q = bid >> 3;
    const int jg = xcd + 8 * (q & 7);     // [0,64)
    const int mb = q >> 3;                // [0,8)
    const int j0 = jg * 32, m0 = mb * 64;
    const int NCKd = 64;

    const int wr = w >> 1, wc = w & 1;
    const ushortT* aPtr = Afr + (size_t)((m0 >> 4) + wr * 2) * (NCKd * 1024) + lane * 8;
    const ushortT* bPtr = Wfr + (size_t)(jg * 2 + wc) * (NCKd * 3072) + lane * 8;

    floatx4 acc[2][3];
#pragma unroll
    for (int mi = 0; mi < 2; ++mi)
#pragma unroll
        for (int g = 0; g < 3; ++g) acc[mi][g] = (floatx4){0.f, 0.f, 0.f, 0.f};

    short8 s0b[6], s0a[4], s1b[6], s1a[4], s2b[6], s2a[4], s3b[6], s3a[4];
    MAIN_LOOP();

    const int colj = j0 + wc * 16 + (lane & 15);
    const float bR = bhD[colj], bZ = bhD[H2 + colj], bN = bhD[2 * H2 + colj];
    const int rloc0 = wr * 32 + (lane >> 4) * 4;
    const int cA = j0 >> 5;
    const int innerB = ((colj >> 3) & 3) * 128 + (colj & 7);
#pragma unroll
    for (int mi = 0; mi < 2; ++mi) {
#pragma unroll
        for (int r = 0; r < 4; ++r) {
            const int rloc = rloc0 + mi * 16 + r;
            const int row = m0 + rloc;
            const float* gi = giTabD + (size_t)tok[row] * H6;
            float ghr = acc[mi][0][r] + bR;
            float ghz = acc[mi][1][r] + bZ;
            float ghn = acc[mi][2][r] + bN;
            float rr = sigmoidf_(gi[colj] + ghr);
            float z  = sigmoidf_(gi[H2 + colj] + ghz);
            float n  = tanhf(gi[2 * H2 + colj] + rr * ghn);
            const size_t idx = (size_t)row * H2 + colj;
            float hnew = (1.0f - z) * n + z * h[idx];
            h[idx] = hnew;
            uintT u = __float_as_uint(hnew);
            const int rbl = wr * 2 + mi;
            const int inner = ((lane >> 4) * 4 + r) * 8 + innerB;
            eb[rbl * 1024 + inner] = (ushortT)(u >> 16);
            eb[rbl * 1024 + 512 + inner] =
                (ushortT)(__float_as_uint(hnew - __uint_as_float(u & 0xFFFF0000u)) >> 16);
        }
    }
    EPILOGUE_STORE(64)
}

// hh fp32 row-major + dec A planes (fragment-major); tok[b]=tgt[b,0]
__global__ __launch_bounds__(256) void init_hh_tok_split(
    const float* __restrict__ h_f, const float* __restrict__ h_b,
    const int* __restrict__ tgt, float* __restrict__ hh,
    ushortT* __restrict__ AfrD, int* __restrict__ tok)
{
    int i = blockIdx.x * blockDim.x + threadIdx.x;   // over B*2H
    int b = i >> 11;
    int j = i & 2047;
    float v = (j < H) ? h_f[(size_t)b * H + j] : h_b[(size_t)b * H + (j - H)];
    hh[i] = v;
    uintT u = __float_as_uint(v);
    size_t ao = (((size_t)(b >> 4) * 64 + (j >> 5)) * 2) * 512
              + (size_t)((b & 15) + 16 * ((j >> 3) & 3)) * 8 + (j & 7);
    AfrD[ao] = (ushortT)(u >> 16);
    AfrD[ao + 512] = (ushortT)(__float_as_uint(v - __uint_as_float(u & 0xFFFF0000u)) >> 16);
    if (j == 0) tok[b] = tgt[b * T];
}

// ===========================================================================
// logits = hh @ W_fc^T + b_fc (V=128) + argmax; 2 rows/block, 256 thr.
// ===========================================================================
__global__ __launch_bounds__(256) void logits_argmax2(
    const float* __restrict__ hh, const float* __restrict__ W_fc,
    const float* __restrict__ b_fc, float* __restrict__ out,
    int* __restrict__ tok, int t)
{
    __shared__ float sh[2][H2];
    __shared__ float sred[2][2][128];
    __shared__ float sval[2][128];
    __shared__ int   sidx[2][128];
    const int tid = threadIdx.x;
    const int col = tid & 127;
    const int kh  = tid >> 7;
    const int b0  = blockIdx.x * 2;

    {
        const float4* srcp = (const float4*)(hh + (size_t)b0 * H2);
        float4* dst = (float4*)sh;
        for (int i = tid; i < 2 * H2 / 4; i += 256) dst[i] = srcp[i];
    }
    __syncthreads();

    const float* wrow = W_fc + (size_t)col * H2 + kh * (H2 / 2);
    const float* s0 = sh[0] + kh * (H2 / 2);
    const float* s1 = sh[1] + kh * (H2 / 2);
    float a0 = 0.f, a1 = 0.f;
#pragma unroll 8
    for (int k = 0; k < H2 / 2; k += 4) {
        float4 w4 = *(const float4*)(wrow + k);
        float4 h0 = *(const float4*)(s0 + k);
        float4 h1 = *(const float4*)(s1 + k);
        a0 += w4.x * h0.x + w4.y * h0.y + w4.z * h0.z + w4.w * h0.w;
        a1 += w4.x * h1.x + w4.y * h1.y + w4.z * h1.z + w4.w * h1.w;
    }
    sred[kh][0][col] = a0;
    sred[kh][1][col] = a1;
    __syncthreads();

    if (kh == 0) {
        float l0 = sred[0][0][col] + sred[1][0][col] + b_fc[col];
        float l1 = sred[0][1][col] + sred[1][1][col] + b_fc[col];
        out[(size_t)(b0 + 0) * ((T - 1) * VOUTD) + (size_t)t * VOUTD + col] = l0;
        out[(size_t)(b0 + 1) * ((T - 1) * VOUTD) + (size_t)t * VOUTD + col] = l1;
        sval[0][col] = l0; sidx[0][col] = col;
        sval[1][col] = l1; sidx[1][col] = col;
    }
    __syncthreads();

    const int r = tid >> 7, c = tid & 127;
    for (int off = 64; off > 0; off >>= 1) {
        if (c < off) {
            float ov = sval[r][c + off]; int oi = sidx[r][c + off];
            if (ov > sval[r][c] || (ov == sval[r][c] && oi < sidx[r][c])) {
                sval[r][c] = ov; sidx[r][c] = oi;
            }
        }
        __syncthreads();
    }
    if (tid < 2) tok[b0 + tid] = sidx[tid][0];
}

// ===========================================================================
// Split-K fp32 GEMM (exact): Cp[z][128,N] = A[:, zKc:(z+1)Kc] @ W[:, ...]^T
// + deterministic combine (sum parts in k-order, then +bias).
// ===========================================================================
__global__ __launch_bounds__(256) void gemm_sk(
    const float* __restrict__ Abase, int lda,
    const float* __restrict__ W, float* __restrict__ Cp, int N, int K, int KS)
{
    __shared__ float As[16][68];
    __shared__ float Ws[16][68];
    const int t = threadIdx.x;
    const int m0 = blockIdx.y * 64, n0 = blockIdx.x * 64;
    const int Kc = K / KS, kb = blockIdx.z * Kc;
    const int lr = t >> 2, lc = (t & 3) << 2;
    const int tx = t & 15, ty = t >> 4;
    const int tn0 = tx << 2, tm0 = ty << 2;
    const float* Aptr = Abase + (size_t)(m0 + lr) * lda + kb;
    const float* Wptr = W + (size_t)(n0 + lr) * K + kb;
    float acc[4][4] = {{0.f}};
    for (int k0 = 0; k0 < Kc; k0 += 16) {
        float4 a4 = *(const float4*)(Aptr + k0 + lc);
        float4 w4 = *(const float4*)(Wptr + k0 + lc);
        __syncthreads();
        As[lc+0][lr] = a4.x; As[lc+1][lr] = a4.y; As[lc+2][lr] = a4.z; As[lc+3][lr] = a4.w;
        Ws[lc+0][lr] = w4.x; Ws[lc+1][lr] = w4.y; Ws[lc+2][lr] = w4.z; Ws[lc+3][lr] = w4.w;
        __syncthreads();
#pragma unroll
        for (int kk = 0; kk < 16; ++kk) {
            float4 av = *(const float4*)&As[kk][tm0];
            float4 wv = *(const float4*)&Ws[kk][tn0];
            float am[4] = {av.x, av.y, av.z, av.w};
            float wn[4] = {wv.x, wv.y, wv.z, wv.w};
#pragma unroll
            for (int i = 0; i < 4; ++i)
#pragma unroll
                for (int j = 0; j < 4; ++j) acc[i][j] += am[i] * wn[j];
        }
    }
    float* Cb = Cp + ((size_t)blockIdx.z * VOUTD + m0 + tm0) * N + n0 + tn0;
#pragma unroll
    for (int i = 0; i < 4; ++i)
        *(float4*)(Cb + (size_t)i * N) = make_float4(acc[i][0], acc[i][1], acc[i][2], acc[i][3]);
}

__global__ __launch_bounds__(256) void gi_combine(
    const float* __restrict__ Cp, const float* __restrict__ bias,
    float* __restrict__ Cout, int N, int KS)
{
    int j = blockIdx.x * 256 + threadIdx.x;
    int v = blockIdx.y;
    float s = 0.f;
    for (int z = 0; z < KS; ++z) s += Cp[((size_t)z * VOUTD + v) * N + j];
    Cout[(size_t)v * N + j] = s + bias[j];
}

// ===========================================================================
// fp32 vector GEMM (fallback path only).
// ===========================================================================
__global__ __launch_bounds__(256) void gemm_bias(
    const float* __restrict__ Abase,
    const int* __restrict__ idx, int idxStride, int idxOff, int lda,
    const float* __restrict__ W, const float* __restrict__ bias,
    float* __restrict__ C, int N, int K)
{
    __shared__ float As[16][68];
    __shared__ float Ws[16][68];
    const int t = threadIdx.x;
    const int m0 = blockIdx.y * 64, n0 = blockIdx.x * 64;
    const int lr = t >> 2, lc = (t & 3) << 2;
    const int tx = t & 15, ty = t >> 4;
    const int tn0 = tx << 2, tm0 = ty << 2;
    const int arow = m0 + lr;
    const float* Aptr = idx ? (Abase + (size_t)idx[arow * idxStride + idxOff] * lda)
                            : (Abase + (size_t)arow * lda);
    const float* Wptr = W + (size_t)(n0 + lr) * K;
    float acc[4][4] = {{0.f}};
    for (int k0 = 0; k0 < K; k0 += 16) {
        float4 a4 = *(const float4*)(Aptr + k0 + lc);
        float4 w4 = *(const float4*)(Wptr + k0 + lc);
        __syncthreads();
        As[lc+0][lr] = a4.x; As[lc+1][lr] = a4.y; As[lc+2][lr] = a4.z; As[lc+3][lr] = a4.w;
        Ws[lc+0][lr] = w4.x; Ws[lc+1][lr] = w4.y; Ws[lc+2][lr] = w4.z; Ws[lc+3][lr] = w4.w;
        __syncthreads();
#pragma unroll
        for (int kk = 0; kk < 16; ++kk) {
            float4 av = *(const float4*)&As[kk][tm0];
            float4 wv = *(const float4*)&Ws[kk][tn0];
            float am[4] = {av.x, av.y, av.z, av.w};
            float wn[4] = {wv.x, wv.y, wv.z, wv.w};
#pragma unroll
            for (int i = 0; i < 4; ++i)
#pragma unroll
                for (int j = 0; j < 4; ++j) acc[i][j] += am[i] * wn[j];
        }
    }
    const float b0 = bias[n0+tn0], b1 = bias[n0+tn0+1], b2 = bias[n0+tn0+2], b3 = bias[n0+tn0+3];
#pragma unroll
    for (int i = 0; i < 4; ++i) {
        float4 o = make_float4(acc[i][0]+b0, acc[i][1]+b1, acc[i][2]+b2, acc[i][3]+b3);
        *(float4*)(C + (size_t)(m0 + tm0 + i) * N + n0 + tn0) = o;
    }
}

__global__ __launch_bounds__(256) void gemm_enc(
    const float* __restrict__ Abase, int lda, int K,
    const int* __restrict__ srcIdx, int s,
    const float* __restrict__ W1, const float* __restrict__ bias1,
    const float* __restrict__ W2, const float* __restrict__ bias2,
    float* __restrict__ C, int N)
{
    __shared__ float As[16][68];
    __shared__ float Ws[16][68];
    const int t = threadIdx.x;
    const int m0 = blockIdx.y * 64, n0 = blockIdx.x * 64;
    const bool bwd = (m0 >= B);
    const float* W = bwd ? W2 : W1;
    const float* bias = bwd ? bias2 : bias1;
    const int lr = t >> 2, lc = (t & 3) << 2;
    const int tx = t & 15, ty = t >> 4;
    const int tn0 = tx << 2, tm0 = ty << 2;
    const int arow = m0 + lr;
    const float* Aptr;
    if (srcIdx) {
        int r = arow & (B - 1);
        int sidx = bwd ? (S - 1 - s) : s;
        Aptr = Abase + (size_t)srcIdx[r * S + sidx] * lda;
    } else Aptr = Abase + (size_t)arow * lda;
    const float* Wptr = W + (size_t)(n0 + lr) * K;
    float acc[4][4] = {{0.f}};
    for (int k0 = 0; k0 < K; k0 += 16) {
        float4 a4 = *(const float4*)(Aptr + k0 + lc);
        float4 w4 = *(const float4*)(Wptr + k0 + lc);
        __syncthreads();
        As[lc+0][lr] = a4.x; As[lc+1][lr] = a4.y; As[lc+2][lr] = a4.z; As[lc+3][lr] = a4.w;
        Ws[lc+0][lr] = w4.x; Ws[lc+1][lr] = w4.y; Ws[lc+2][lr] = w4.z; Ws[lc+3][lr] = w4.w;
        __syncthreads();
#pragma unroll
        for (int kk = 0; kk < 16; ++kk) {
            float4 av = *(const float4*)&As[kk][tm0];
            float4 wv = *(const float4*)&Ws[kk][tn0];
            float am[4] = {av.x, av.y, av.z, av.w};
            float wn[4] = {wv.x, wv.y, wv.z, wv.w};
#pragma unroll
            for (int i = 0; i < 4; ++i)
#pragma unroll
                for (int j = 0; j < 4; ++j) acc[i][j] += am[i] * wn[j];
        }
    }
    const float b0 = bias[n0+tn0], b1 = bias[n0+tn0+1], b2 = bias[n0+tn0+2], b3 = bias[n0+tn0+3];
#pragma unroll
    for (int i = 0; i < 4; ++i) {
        float4 o = make_float4(acc[i][0]+b0, acc[i][1]+b1, acc[i][2]+b2, acc[i][3]+b3);
        *(float4*)(C + (size_t)(m0 + tm0 + i) * N + n0 + tn0) = o;
    }
}

__global__ __launch_bounds__(256) void gru_gate(
    const float* __restrict__ gi, const float* __restrict__ gh,
    float* __restrict__ h, int Hd)
{
    int i = blockIdx.x * blockDim.x + threadIdx.x;
    int b = i / Hd, j = i - b * Hd;
    const float* gib = gi + (size_t)b * 3 * Hd;
    const float* ghb = gh + (size_t)b * 3 * Hd;
    float r = sigmoidf_(gib[j] + ghb[j]);
    float z = sigmoidf_(gib[Hd + j] + ghb[Hd + j]);
    float n = tanhf(gib[2 * Hd + j] + r * ghb[2 * Hd + j]);
    h[i] = (1.0f - z) * n + z * h[i];
}

__global__ __launch_bounds__(256) void init_hh_tok(
    const float* __restrict__ h_f, const float* __restrict__ h_b,
    const int* __restrict__ tgt, float* __restrict__ hh, int* __restrict__ tok)
{
    int i = blockIdx.x * blockDim.x + threadIdx.x;
    int b = i >> 11, j = i & 2047;
    hh[i] = (j < H) ? h_f[(size_t)b * H + j] : h_b[(size_t)b * H + (j - H)];
    if (j == 0) tok[b] = tgt[b * T];
}

// ===========================================================================
extern "C" void kernel_launch(void* const* d_in, const int* in_sizes, int n_in,
                              void* d_out, int out_size, void* d_ws, size_t ws_size,
                              hipStream_t stream)
{
    const int*   src     = (const int*)d_in[0];
    const int*   tgt     = (const int*)d_in[1];
    const float* enc_emb = (const float*)d_in[2];
    const float* dec_emb = (const float*)d_in[3];
    const float* W_ih_f  = (const float*)d_in[4];
    const float* W_hh_f  = (const float*)d_in[5];
    const float* b_ih_f  = (const float*)d_in[6];
    const float* b_hh_f  = (const float*)d_in[7];
    const float* W_ih_b  = (const float*)d_in[8];
    const float* W_hh_b  = (const float*)d_in[9];
    const float* b_ih_b  = (const float*)d_in[10];
    const float* b_hh_b  = (const float*)d_in[11];
    const float* W_ih_d  = (const float*)d_in[12];
    const float* W_hh_d  = (const float*)d_in[13];
    const float* b_ih_d  = (const float*)d_in[14];
    const float* b_hh_d  = (const float*)d_in[15];
    const float* W_fc    = (const float*)d_in[16];
    const float* b_fc    = (const float*)d_in[17];
    float* out = (float*)d_out;

    // ---------------- workspace layout ----------------
    char* base = (char*)d_ws;
    size_t off = 0;
    auto alloc = [&](size_t bytes) { char* p = base + off; off += (bytes + 255) & ~(size_t)255; return p; };

    float*   hE     = (float*)  alloc((size_t)2 * B * H * 4);       // zeroed with AfrEA
    ushortT* AfrEA  = (ushortT*)alloc((size_t)2 * B * H * 2 * 2);   // enc A planes ping
    ushortT* AfrEB  = (ushortT*)alloc((size_t)2 * B * H * 2 * 2);   // enc A planes pong
    float*   hh     = (float*)  alloc((size_t)B * H2 * 4);
    ushortT* AfrDA  = (ushortT*)alloc((size_t)B * H2 * 2 * 2);      // dec A planes ping
    ushortT* AfrDB  = (ushortT*)alloc((size_t)B * H2 * 2 * 2);      // dec A planes pong
    float*   giTabF = (float*)  alloc((size_t)VOUTD * H3 * 4);
    float*   giTabB = (float*)  alloc((size_t)VOUTD * H3 * 4);
    float*   giTabD = (float*)  alloc((size_t)VOUTD * H6 * 4);
    float*   giPart = (float*)  alloc((size_t)4 * VOUTD * H6 * 4);  // split-K partials
    ushortT* WfrF   = (ushortT*)alloc((size_t)H3 * H * 2 * 2);
    ushortT* WfrB   = (ushortT*)alloc((size_t)H3 * H * 2 * 2);
    ushortT* WfrD   = (ushortT*)alloc((size_t)H6 * H2 * 2 * 2);
    int*     tok    = (int*)    alloc((size_t)B * 4);
    size_t required = off;

    dim3 blk(256);

    if (ws_size >= required) {
        // =================== fragment-major fused path ===================
        {   // zero hE fp32 + AfrEA (contiguous)
            size_t zbytes = (size_t)2 * B * H * 4 + (size_t)2 * B * H * 4;
            int n16 = (int)(zbytes / 16);
            zero16<<<dim3((n16 + 255) / 256), blk, 0, stream>>>((uint4*)hE, n16);
        }
        // W -> fragment-major hi/lo (coalesced, wave per fragment)
        {
            int fe = (H / 16) * (H / 32) * 3;        // 6144
            int fd = (H2 / 16) * (H2 / 32) * 3;      // 24576
            swizzle_w<<<dim3((fe + 3) / 4), blk, 0, stream>>>(W_hh_f, WfrF, 10, 7);
            swizzle_w<<<dim3((fe + 3) / 4), blk, 0, stream>>>(W_hh_b, WfrB, 10, 7);
            swizzle_w<<<dim3((fd + 3) / 4), blk, 0, stream>>>(W_hh_d, WfrD, 11, 8);
        }

        // gi tables (exact fp32, split-K x4)
        gemm_sk<<<dim3(H3 / 64, VOUTD / 64, 4), blk, 0, stream>>>(
            enc_emb, E, W_ih_f, giPart, H3, E, 4);
        gi_combine<<<dim3(H3 / 256, VOUTD), blk, 0, stream>>>(giPart, b_ih_f, giTabF, H3, 4);
        gemm_sk<<<dim3(H3 / 64, VOUTD / 64, 4), blk, 0, stream>>>(
            enc_emb, E, W_ih_b, giPart, H3, E, 4);
        gi_combine<<<dim3(H3 / 256, VOUTD), blk, 0, stream>>>(giPart, b_ih_b, giTabB, H3, 4);
        gemm_sk<<<dim3(H6 / 64, VOUTD / 64, 4), blk, 0, stream>>>(
            dec_emb, E, W_ih_d, giPart, H6, E, 4);
        gi_combine<<<dim3(H6 / 256, VOUTD), blk, 0, stream>>>(giPart, b_ih_d, giTabD, H6, 4);

        // ---------------- Encoder: 64 fused steps ----------------
        for (int s = 0; s < S; ++s) {
            const ushortT* inA = (s & 1) ? AfrEB : AfrEA;
            ushortT* outA = (s & 1) ? AfrEA : AfrEB;
            fused_step_enc<<<dim3(512), blk, 0, stream>>>(
                inA, WfrF, WfrB, giTabF, giTabB, src, s, b_hh_f, b_hh_b, hE, outA);
        }

        init_hh_tok_split<<<dim3((B * H2) / 256), blk, 0, stream>>>(
            hE, hE + (size_t)B * H, tgt, hh, AfrDA, tok);

        // ---------------- Decoder: 31 fused steps ----------------
        for (int t = 0; t < T - 1; ++t) {
            const ushortT* inA = (t & 1) ? AfrDB : AfrDA;
            ushortT* outA = (t & 1) ? AfrDA : AfrDB;
            fused_step_dec<<<dim3(512), blk, 0, stream>>>(
                inA, WfrD, giTabD, tok, b_hh_d, hh, outA);
            logits_argmax2<<<dim3(B / 2), blk, 0, stream>>>(hh, W_fc, b_fc, out, tok, t);
        }
    } else {
        // =================== fp32 fallback (R1-proven path) ===================
        {
            size_t zbytes = (size_t)2 * B * H * 4;
            int n16 = (int)(zbytes / 16);
            zero16<<<dim3((n16 + 255) / 256), blk, 0, stream>>>((uint4*)hE, n16);
        }
        float* giE = (float*)WfrF;                       // scratch overlay
        float* ghF = giE + (size_t)2 * B * H3;
        dim3 grid_gi(H3 / 64, (2 * B) / 64);
        dim3 grid_gate((2 * B * H) / 256);
        for (int s = 0; s < S; ++s) {
            gemm_enc<<<grid_gi, blk, 0, stream>>>(enc_emb, E, E, src, s,
                                                  W_ih_f, b_ih_f, W_ih_b, b_ih_b, giE, H3);
            gemm_enc<<<grid_gi, blk, 0, stream>>>(hE, H, H, nullptr, 0,
                                                  W_hh_f, b_hh_f, W_hh_b, b_hh_b, ghF, H3);
            gru_gate<<<grid_gate, blk, 0, stream>>>(giE, ghF, hE, H);
        }
        init_hh_tok<<<dim3((B * H2) / 256), blk, 0, stream>>>(hE, hE + (size_t)B * H, tgt, hh, tok);
        dim3 grid_d(H6 / 64, B / 64);
        dim3 grid_dgate((B * H2) / 256);
        for (int t = 0; t < T - 1; ++t) {
            gemm_bias<<<grid_d, blk, 0, stream>>>(dec_emb, tok, 1, 0, E,
                                                  W_ih_d, b_ih_d, giE, H6, E);
            gemm_bias<<<grid_d, blk, 0, stream>>>(hh, nullptr, 0, 0, H2,
                                                  W_hh_d, b_hh_d, ghF, H6, H2);
            gru_gate<<<grid_dgate, blk, 0, stream>>>(giE, ghF, hh, H2);
            logits_argmax2<<<dim3(B / 2), blk, 0, stream>>>(hh, W_fc, b_fc, out, tok, t);
        }
    }
}

// Round 9
// 4804.730 us; speedup vs baseline: 1.1644x; 1.1644x over previous
//
#include <hip/hip_runtime.h>
#include <math.h>

#define B 512
#define S 64
#define T 32
#define E 512
#define H 1024
#define VOUTD 128
#define H2 (2*H)
#define H3 (3*H)
#define H6 (6*H)

typedef unsigned short ushortT;
typedef unsigned int uintT;
typedef __attribute__((ext_vector_type(8))) short short8;
typedef __attribute__((ext_vector_type(4))) float floatx4;

__device__ __forceinline__ float sigmoidf_(float x) { return 1.0f / (1.0f + expf(-x)); }

__device__ __forceinline__ uintT pack_hi2(float a, float b) {
    return (__float_as_uint(a) >> 16) | (__float_as_uint(b) & 0xFFFF0000u);
}
__device__ __forceinline__ uintT pack_lo2(float a, float b) {
    uintT ua = __float_as_uint(a), ub = __float_as_uint(b);
    uintT la = __float_as_uint(a - __uint_as_float(ua & 0xFFFF0000u)) >> 16;
    uintT lb = __float_as_uint(b - __uint_as_float(ub & 0xFFFF0000u)) >> 16;
    return la | (lb << 16);
}

__global__ __launch_bounds__(256) void zero16(uint4* __restrict__ p, int n)
{
    int i = blockIdx.x * 256 + threadIdx.x;
    if (i < n) p[i] = make_uint4(0u, 0u, 0u, 0u);
}

// ===========================================================================
// W -> fragment-major hi/lo planes. COALESCED: one wave per fragment.
// Fragment f = (jb*ncK + c)*3 + g; 1024 shorts (hi 512 | lo 512).
// ncK = K/32 = 1 << (kShift-2)  =>  jb = rest >> (kShift-2).
// ===========================================================================
__global__ __launch_bounds__(256) void swizzle_w(
    const float* __restrict__ W, ushortT* __restrict__ out, int njShift, int kShift)
{
    const int K = 8 << kShift;
    const int nj = 1 << njShift;
    const int ncK = K >> 5;
    const int total = (nj >> 4) * ncK * 3;
    int f = blockIdx.x * 4 + (threadIdx.x >> 6);
    if (f >= total) return;
    const int lane = threadIdx.x & 63;
    int g = f % 3;
    int rest = f / 3;
    int c = rest & (ncK - 1);
    int jb = rest >> (kShift - 2);
    int jl = lane & 15, kq = lane >> 4;
    int row = g * nj + jb * 16 + jl;
    int k = c * 32 + kq * 8;
    const float* s = W + (size_t)row * K + k;
    float4 f0 = *(const float4*)s;
    float4 f1 = *(const float4*)(s + 4);
    uint4 hv = make_uint4(pack_hi2(f0.x, f0.y), pack_hi2(f0.z, f0.w),
                          pack_hi2(f1.x, f1.y), pack_hi2(f1.z, f1.w));
    uint4 lv = make_uint4(pack_lo2(f0.x, f0.y), pack_lo2(f0.z, f0.w),
                          pack_lo2(f1.x, f1.y), pack_lo2(f1.z, f1.w));
    size_t base = (size_t)f * 1024 + (size_t)lane * 8;
    *(uint4*)(out + base) = hv;
    *(uint4*)(out + base + 512) = lv;
}

// ===========================================================================
// Barrier-free streaming main loop, TALL wave tiles: wave = 64 rows x 16 j
// (acc[4][3]); block = 4 waves stacked by rows (256 rows x 16 j), so all 4
// waves read the SAME B fragments each chunk (CU-local L1 reuse; grid = 256
// blocks = 1/CU). 2-deep register ping-pong (R7-proven); no LDS/barriers in
// the loop. Per-acc MFMA order: Ah*Bh, Ah*Bl, Al*Bh; chunks ascending --
// bit-identical numerics to R3..R8.
// ===========================================================================
#define MFMA16(a, b, c) __builtin_amdgcn_mfma_f32_16x16x32_bf16(a, b, c, 0, 0, 0)

#define LOADSET(SET, C)                                                         \
    {                                                                           \
        const ushortT* bp_ = bPtr + (size_t)(C) * 3072;                         \
        SET##b[0] = *(const short8*)(bp_);                                      \
        SET##b[1] = *(const short8*)(bp_ + 512);                                \
        SET##b[2] = *(const short8*)(bp_ + 1024);                               \
        SET##b[3] = *(const short8*)(bp_ + 1536);                               \
        SET##b[4] = *(const short8*)(bp_ + 2048);                               \
        SET##b[5] = *(const short8*)(bp_ + 2560);                               \
        _Pragma("unroll")                                                       \
        for (int rb_ = 0; rb_ < 4; ++rb_) {                                     \
            const ushortT* ap_ = aPtr + (size_t)rb_ * (NCKd * 1024)             \
                                      + (size_t)(C) * 1024;                     \
            SET##a[rb_ * 2]     = *(const short8*)(ap_);                        \
            SET##a[rb_ * 2 + 1] = *(const short8*)(ap_ + 512);                  \
        }                                                                       \
    }

#define COMPSET(SET)                                                            \
    _Pragma("unroll")                                                           \
    for (int g = 0; g < 3; ++g) {                                               \
        short8 bh_ = SET##b[g * 2], bl_ = SET##b[g * 2 + 1];                    \
        _Pragma("unroll")                                                       \
        for (int mi = 0; mi < 4; ++mi) {                                        \
            acc[mi][g] = MFMA16(SET##a[mi * 2], bh_, acc[mi][g]);               \
            acc[mi][g] = MFMA16(SET##a[mi * 2], bl_, acc[mi][g]);               \
            acc[mi][g] = MFMA16(SET##a[mi * 2 + 1], bh_, acc[mi][g]);           \
        }                                                                       \
    }

#define MAIN_LOOP()                                                             \
    LOADSET(s0, 0);                                                             \
    for (int c = 0; c < NCKd; c += 2) {                                         \
        LOADSET(s1, c + 1);                                                     \
        COMPSET(s0);                                                            \
        if (c + 2 < NCKd) LOADSET(s0, c + 2);                                   \
        COMPSET(s1);                                                            \
    }

// Epilogue A-plane store: wave w owns rowblocks w*4+mi and the kqpar-half of
// each fragment (jg16 parity). Stage 16 rb x (256 hi + 256 lo) shorts in LDS,
// one barrier, then 32 x 512B contiguous runs (8 thr x 64B each).
#define EPILOGUE_STORE(NCKA)                                                    \
    __syncthreads();                                                            \
    {                                                                           \
        const int run = t >> 3;            /* 0..31 */                          \
        const int rb_ = run >> 1;          /* 0..15 */                          \
        const int pl_ = run & 1;           /* hi/lo */                          \
        const int sub = t & 7;                                                  \
        const ushortT* sp = &eb[rb_][pl_ * 256 + sub * 32];                     \
        ushortT* dp = AfrOut + (((size_t)((m0 >> 4) + rb_)) * (NCKA) + cA) * 1024 \
                    + pl_ * 512 + kqpar * 256 + sub * 32;                       \
        _Pragma("unroll")                                                       \
        for (int v = 0; v < 4; ++v)                                             \
            *(uint4*)(dp + v * 8) = *(const uint4*)(sp + v * 8);                \
    }

// ===========================================================================
// FUSED encoder step. Block = 256 rows x 16 j, 4 row-stacked waves.
// Grid 256 = 8 xcd x (8 jg16-offsets x 4 mb). Barrier-free main loop.
// ===========================================================================
__global__ __launch_bounds__(256, 1) void fused_step_enc(
    const ushortT* __restrict__ Afr,
    const ushortT* __restrict__ WfrF, const ushortT* __restrict__ WfrB,
    const float* __restrict__ giTabF, const float* __restrict__ giTabB,
    const int* __restrict__ src, int s,
    const float* __restrict__ bhF, const float* __restrict__ bhB,
    float* __restrict__ h, ushortT* __restrict__ AfrOut)
{
    __shared__ ushortT eb[16][512];       // 16 KB epilogue staging
    const int t = threadIdx.x, lane = t & 63, w = t >> 6;
    const int bid = blockIdx.x;
    const int xcd = bid & 7, q = bid >> 3;
    const int jg16 = xcd * 8 + (q & 7);   // [0,64)
    const int mb   = q >> 3;              // [0,4)
    const int j0 = jg16 * 16, m0 = mb * 256;
    const bool bwd = (m0 >= B);
    const ushortT* Wfr = bwd ? WfrB : WfrF;
    const float* giTab = bwd ? giTabB : giTabF;
    const float* bh = bwd ? bhB : bhF;
    const int NCKd = 32;
    const int sidx = bwd ? (S - 1 - s) : s;

    const ushortT* aPtr = Afr + (size_t)((m0 >> 4) + w * 4) * (NCKd * 1024) + lane * 8;
    const ushortT* bPtr = Wfr + (size_t)jg16 * (NCKd * 3072) + lane * 8;

    floatx4 acc[4][3];
#pragma unroll
    for (int mi = 0; mi < 4; ++mi)
#pragma unroll
        for (int g = 0; g < 3; ++g) acc[mi][g] = (floatx4){0.f, 0.f, 0.f, 0.f};

    short8 s0b[6], s0a[8], s1b[6], s1a[8];
    MAIN_LOOP();

    // fused gate epilogue
    const int colj = j0 + (lane & 15);
    const float bR = bh[colj], bZ = bh[H + colj], bN = bh[2 * H + colj];
    const int cA = jg16 >> 1;
    const int kqpar = jg16 & 1;
    const int khalf = (lane >> 3) & 1;
    const int e7 = lane & 7;
#pragma unroll
    for (int mi = 0; mi < 4; ++mi) {
#pragma unroll
        for (int r = 0; r < 4; ++r) {
            const int r15 = (lane >> 4) * 4 + r;
            const int row = m0 + w * 64 + mi * 16 + r15;
            const int tk = src[(row & (B - 1)) * S + sidx];
            const float* gi = giTab + (size_t)tk * H3;
            float ghr = acc[mi][0][r] + bR;
            float ghz = acc[mi][1][r] + bZ;
            float ghn = acc[mi][2][r] + bN;
            float rr = sigmoidf_(gi[colj] + ghr);
            float z  = sigmoidf_(gi[H + colj] + ghz);
            float n  = tanhf(gi[2 * H + colj] + rr * ghn);
            const size_t idx = (size_t)row * H + colj;
            float hnew = (1.0f - z) * n + z * h[idx];
            h[idx] = hnew;
            uintT u = __float_as_uint(hnew);
            const int slot = (r15 + 16 * khalf) * 8 + e7;
            eb[w * 4 + mi][slot] = (ushortT)(u >> 16);
            eb[w * 4 + mi][256 + slot] =
                (ushortT)(__float_as_uint(hnew - __uint_as_float(u & 0xFFFF0000u)) >> 16);
        }
    }
    EPILOGUE_STORE(32)
}

// ===========================================================================
// FUSED decoder step: Hd = 2H, gates {j, 2H+j, 4H+j}. Same structure.
// Grid 256 = 8 xcd x (16 jg16-offsets x 2 mb).
// ===========================================================================
__global__ __launch_bounds__(256, 1) void fused_step_dec(
    const ushortT* __restrict__ Afr, const ushortT* __restrict__ Wfr,
    const float* __restrict__ giTabD, const int* __restrict__ tok,
    const float* __restrict__ bhD,
    float* __restrict__ h, ushortT* __restrict__ AfrOut)
{
    __shared__ ushortT eb[16][512];
    const int t = threadIdx.x, lane = t & 63, w = t >> 6;
    const int bid = blockIdx.x;
    const int xcd = bid & 7, q = bid >> 3;
    const int jg16 = xcd * 16 + (q & 15); // [0,128)
    const int mb   = q >> 4;              // [0,2)
    const int j0 = jg16 * 16, m0 = mb * 256;
    const int NCKd = 64;

    const ushortT* aPtr = Afr + (size_t)((m0 >> 4) + w * 4) * (NCKd * 1024) + lane * 8;
    const ushortT* bPtr = Wfr + (size_t)jg16 * (NCKd * 3072) + lane * 8;

    floatx4 acc[4][3];
#pragma unroll
    for (int mi = 0; mi < 4; ++mi)
#pragma unroll
        for (int g = 0; g < 3; ++g) acc[mi][g] = (floatx4){0.f, 0.f, 0.f, 0.f};

    short8 s0b[6], s0a[8], s1b[6], s1a[8];
    MAIN_LOOP();

    const int colj = j0 + (lane & 15);
    const float bR = bhD[colj], bZ = bhD[H2 + colj], bN = bhD[2 * H2 + colj];
    const int cA = jg16 >> 1;
    const int kqpar = jg16 & 1;
    const int khalf = (lane >> 3) & 1;
    const int e7 = lane & 7;
#pragma unroll
    for (int mi = 0; mi < 4; ++mi) {
#pragma unroll
        for (int r = 0; r < 4; ++r) {
            const int r15 = (lane >> 4) * 4 + r;
            const int row = m0 + w * 64 + mi * 16 + r15;
            const float* gi = giTabD + (size_t)tok[row] * H6;
            float ghr = acc[mi][0][r] + bR;
            float ghz = acc[mi][1][r] + bZ;
            float ghn = acc[mi][2][r] + bN;
            float rr = sigmoidf_(gi[colj] + ghr);
            float z  = sigmoidf_(gi[H2 + colj] + ghz);
            float n  = tanhf(gi[2 * H2 + colj] + rr * ghn);
            const size_t idx = (size_t)row * H2 + colj;
            float hnew = (1.0f - z) * n + z * h[idx];
            h[idx] = hnew;
            uintT u = __float_as_uint(hnew);
            const int slot = (r15 + 16 * khalf) * 8 + e7;
            eb[w * 4 + mi][slot] = (ushortT)(u >> 16);
            eb[w * 4 + mi][256 + slot] =
                (ushortT)(__float_as_uint(hnew - __uint_as_float(u & 0xFFFF0000u)) >> 16);
        }
    }
    EPILOGUE_STORE(64)
}

// hh fp32 row-major + dec A planes (fragment-major); tok[b]=tgt[b,0]
__global__ __launch_bounds__(256) void init_hh_tok_split(
    const float* __restrict__ h_f, const float* __restrict__ h_b,
    const int* __restrict__ tgt, float* __restrict__ hh,
    ushortT* __restrict__ AfrD, int* __restrict__ tok)
{
    int i = blockIdx.x * blockDim.x + threadIdx.x;   // over B*2H
    int b = i >> 11;
    int j = i & 2047;
    float v = (j < H) ? h_f[(size_t)b * H + j] : h_b[(size_t)b * H + (j - H)];
    hh[i] = v;
    uintT u = __float_as_uint(v);
    size_t ao = (((size_t)(b >> 4) * 64 + (j >> 5)) * 2) * 512
              + (size_t)((b & 15) + 16 * ((j >> 3) & 3)) * 8 + (j & 7);
    AfrD[ao] = (ushortT)(u >> 16);
    AfrD[ao + 512] = (ushortT)(__float_as_uint(v - __uint_as_float(u & 0xFFFF0000u)) >> 16);
    if (j == 0) tok[b] = tgt[b * T];
}

// ===========================================================================
// logits = hh @ W_fc^T + b_fc (V=128) + argmax; 2 rows/block, 256 thr.
// ===========================================================================
__global__ __launch_bounds__(256) void logits_argmax2(
    const float* __restrict__ hh, const float* __restrict__ W_fc,
    const float* __restrict__ b_fc, float* __restrict__ out,
    int* __restrict__ tok, int t)
{
    __shared__ float sh[2][H2];
    __shared__ float sred[2][2][128];
    __shared__ float sval[2][128];
    __shared__ int   sidx[2][128];
    const int tid = threadIdx.x;
    const int col = tid & 127;
    const int kh  = tid >> 7;
    const int b0  = blockIdx.x * 2;

    {
        const float4* srcp = (const float4*)(hh + (size_t)b0 * H2);
        float4* dst = (float4*)sh;
        for (int i = tid; i < 2 * H2 / 4; i += 256) dst[i] = srcp[i];
    }
    __syncthreads();

    const float* wrow = W_fc + (size_t)col * H2 + kh * (H2 / 2);
    const float* s0 = sh[0] + kh * (H2 / 2);
    const float* s1 = sh[1] + kh * (H2 / 2);
    float a0 = 0.f, a1 = 0.f;
#pragma unroll 8
    for (int k = 0; k < H2 / 2; k += 4) {
        float4 w4 = *(const float4*)(wrow + k);
        float4 h0 = *(const float4*)(s0 + k);
        float4 h1 = *(const float4*)(s1 + k);
        a0 += w4.x * h0.x + w4.y * h0.y + w4.z * h0.z + w4.w * h0.w;
        a1 += w4.x * h1.x + w4.y * h1.y + w4.z * h1.z + w4.w * h1.w;
    }
    sred[kh][0][col] = a0;
    sred[kh][1][col] = a1;
    __syncthreads();

    if (kh == 0) {
        float l0 = sred[0][0][col] + sred[1][0][col] + b_fc[col];
        float l1 = sred[0][1][col] + sred[1][1][col] + b_fc[col];
        out[(size_t)(b0 + 0) * ((T - 1) * VOUTD) + (size_t)t * VOUTD + col] = l0;
        out[(size_t)(b0 + 1) * ((T - 1) * VOUTD) + (size_t)t * VOUTD + col] = l1;
        sval[0][col] = l0; sidx[0][col] = col;
        sval[1][col] = l1; sidx[1][col] = col;
    }
    __syncthreads();

    const int r = tid >> 7, c = tid & 127;
    for (int off = 64; off > 0; off >>= 1) {
        if (c < off) {
            float ov = sval[r][c + off]; int oi = sidx[r][c + off];
            if (ov > sval[r][c] || (ov == sval[r][c] && oi < sidx[r][c])) {
                sval[r][c] = ov; sidx[r][c] = oi;
            }
        }
        __syncthreads();
    }
    if (tid < 2) tok[b0 + tid] = sidx[tid][0];
}

// ===========================================================================
// Split-K fp32 GEMM (exact) + deterministic combine (gi tables).
// ===========================================================================
__global__ __launch_bounds__(256) void gemm_sk(
    const float* __restrict__ Abase, int lda,
    const float* __restrict__ W, float* __restrict__ Cp, int N, int K, int KS)
{
    __shared__ float As[16][68];
    __shared__ float Ws[16][68];
    const int t = threadIdx.x;
    const int m0 = blockIdx.y * 64, n0 = blockIdx.x * 64;
    const int Kc = K / KS, kb = blockIdx.z * Kc;
    const int lr = t >> 2, lc = (t & 3) << 2;
    const int tx = t & 15, ty = t >> 4;
    const int tn0 = tx << 2, tm0 = ty << 2;
    const float* Aptr = Abase + (size_t)(m0 + lr) * lda + kb;
    const float* Wptr = W + (size_t)(n0 + lr) * K + kb;
    float acc[4][4] = {{0.f}};
    for (int k0 = 0; k0 < Kc; k0 += 16) {
        float4 a4 = *(const float4*)(Aptr + k0 + lc);
        float4 w4 = *(const float4*)(Wptr + k0 + lc);
        __syncthreads();
        As[lc+0][lr] = a4.x; As[lc+1][lr] = a4.y; As[lc+2][lr] = a4.z; As[lc+3][lr] = a4.w;
        Ws[lc+0][lr] = w4.x; Ws[lc+1][lr] = w4.y; Ws[lc+2][lr] = w4.z; Ws[lc+3][lr] = w4.w;
        __syncthreads();
#pragma unroll
        for (int kk = 0; kk < 16; ++kk) {
            float4 av = *(const float4*)&As[kk][tm0];
            float4 wv = *(const float4*)&Ws[kk][tn0];
            float am[4] = {av.x, av.y, av.z, av.w};
            float wn[4] = {wv.x, wv.y, wv.z, wv.w};
#pragma unroll
            for (int i = 0; i < 4; ++i)
#pragma unroll
                for (int j = 0; j < 4; ++j) acc[i][j] += am[i] * wn[j];
        }
    }
    float* Cb = Cp + ((size_t)blockIdx.z * VOUTD + m0 + tm0) * N + n0 + tn0;
#pragma unroll
    for (int i = 0; i < 4; ++i)
        *(float4*)(Cb + (size_t)i * N) = make_float4(acc[i][0], acc[i][1], acc[i][2], acc[i][3]);
}

__global__ __launch_bounds__(256) void gi_combine(
    const float* __restrict__ Cp, const float* __restrict__ bias,
    float* __restrict__ Cout, int N, int KS)
{
    int j = blockIdx.x * 256 + threadIdx.x;
    int v = blockIdx.y;
    float s = 0.f;
    for (int z = 0; z < KS; ++z) s += Cp[((size_t)z * VOUTD + v) * N + j];
    Cout[(size_t)v * N + j] = s + bias[j];
}

// ===========================================================================
// fp32 vector GEMM (fallback path only).
// ===========================================================================
__global__ __launch_bounds__(256) void gemm_bias(
    const float* __restrict__ Abase,
    const int* __restrict__ idx, int idxStride, int idxOff, int lda,
    const float* __restrict__ W, const float* __restrict__ bias,
    float* __restrict__ C, int N, int K)
{
    __shared__ float As[16][68];
    __shared__ float Ws[16][68];
    const int t = threadIdx.x;
    const int m0 = blockIdx.y * 64, n0 = blockIdx.x * 64;
    const int lr = t >> 2, lc = (t & 3) << 2;
    const int tx = t & 15, ty = t >> 4;
    const int tn0 = tx << 2, tm0 = ty << 2;
    const int arow = m0 + lr;
    const float* Aptr = idx ? (Abase + (size_t)idx[arow * idxStride + idxOff] * lda)
                            : (Abase + (size_t)arow * lda);
    const float* Wptr = W + (size_t)(n0 + lr) * K;
    float acc[4][4] = {{0.f}};
    for (int k0 = 0; k0 < K; k0 += 16) {
        float4 a4 = *(const float4*)(Aptr + k0 + lc);
        float4 w4 = *(const float4*)(Wptr + k0 + lc);
        __syncthreads();
        As[lc+0][lr] = a4.x; As[lc+1][lr] = a4.y; As[lc+2][lr] = a4.z; As[lc+3][lr] = a4.w;
        Ws[lc+0][lr] = w4.x; Ws[lc+1][lr] = w4.y; Ws[lc+2][lr] = w4.z; Ws[lc+3][lr] = w4.w;
        __syncthreads();
#pragma unroll
        for (int kk = 0; kk < 16; ++kk) {
            float4 av = *(const float4*)&As[kk][tm0];
            float4 wv = *(const float4*)&Ws[kk][tn0];
            float am[4] = {av.x, av.y, av.z, av.w};
            float wn[4] = {wv.x, wv.y, wv.z, wv.w};
#pragma unroll
            for (int i = 0; i < 4; ++i)
#pragma unroll
                for (int j = 0; j < 4; ++j) acc[i][j] += am[i] * wn[j];
        }
    }
    const float b0 = bias[n0+tn0], b1 = bias[n0+tn0+1], b2 = bias[n0+tn0+2], b3 = bias[n0+tn0+3];
#pragma unroll
    for (int i = 0; i < 4; ++i) {
        float4 o = make_float4(acc[i][0]+b0, acc[i][1]+b1, acc[i][2]+b2, acc[i][3]+b3);
        *(float4*)(C + (size_t)(m0 + tm0 + i) * N + n0 + tn0) = o;
    }
}

__global__ __launch_bounds__(256) void gemm_enc(
    const float* __restrict__ Abase, int lda, int K,
    const int* __restrict__ srcIdx, int s,
    const float* __restrict__ W1, const float* __restrict__ bias1,
    const float* __restrict__ W2, const float* __restrict__ bias2,
    float* __restrict__ C, int N)
{
    __shared__ float As[16][68];
    __shared__ float Ws[16][68];
    const int t = threadIdx.x;
    const int m0 = blockIdx.y * 64, n0 = blockIdx.x * 64;
    const bool bwd = (m0 >= B);
    const float* W = bwd ? W2 : W1;
    const float* bias = bwd ? bias2 : bias1;
    const int lr = t >> 2, lc = (t & 3) << 2;
    const int tx = t & 15, ty = t >> 4;
    const int tn0 = tx << 2, tm0 = ty << 2;
    const int arow = m0 + lr;
    const float* Aptr;
    if (srcIdx) {
        int r = arow & (B - 1);
        int sidx = bwd ? (S - 1 - s) : s;
        Aptr = Abase + (size_t)srcIdx[r * S + sidx] * lda;
    } else Aptr = Abase + (size_t)arow * lda;
    const float* Wptr = W + (size_t)(n0 + lr) * K;
    float acc[4][4] = {{0.f}};
    for (int k0 = 0; k0 < K; k0 += 16) {
        float4 a4 = *(const float4*)(Aptr + k0 + lc);
        float4 w4 = *(const float4*)(Wptr + k0 + lc);
        __syncthreads();
        As[lc+0][lr] = a4.x; As[lc+1][lr] = a4.y; As[lc+2][lr] = a4.z; As[lc+3][lr] = a4.w;
        Ws[lc+0][lr] = w4.x; Ws[lc+1][lr] = w4.y; Ws[lc+2][lr] = w4.z; Ws[lc+3][lr] = w4.w;
        __syncthreads();
#pragma unroll
        for (int kk = 0; kk < 16; ++kk) {
            float4 av = *(const float4*)&As[kk][tm0];
            float4 wv = *(const float4*)&Ws[kk][tn0];
            float am[4] = {av.x, av.y, av.z, av.w};
            float wn[4] = {wv.x, wv.y, wv.z, wv.w};
#pragma unroll
            for (int i = 0; i < 4; ++i)
#pragma unroll
                for (int j = 0; j < 4; ++j) acc[i][j] += am[i] * wn[j];
        }
    }
    const float b0 = bias[n0+tn0], b1 = bias[n0+tn0+1], b2 = bias[n0+tn0+2], b3 = bias[n0+tn0+3];
#pragma unroll
    for (int i = 0; i < 4; ++i) {
        float4 o = make_float4(acc[i][0]+b0, acc[i][1]+b1, acc[i][2]+b2, acc[i][3]+b3);
        *(float4*)(C + (size_t)(m0 + tm0 + i) * N + n0 + tn0) = o;
    }
}

__global__ __launch_bounds__(256) void gru_gate(
    const float* __restrict__ gi, const float* __restrict__ gh,
    float* __restrict__ h, int Hd)
{
    int i = blockIdx.x * blockDim.x + threadIdx.x;
    int b = i / Hd, j = i - b * Hd;
    const float* gib = gi + (size_t)b * 3 * Hd;
    const float* ghb = gh + (size_t)b * 3 * Hd;
    float r = sigmoidf_(gib[j] + ghb[j]);
    float z = sigmoidf_(gib[Hd + j] + ghb[Hd + j]);
    float n = tanhf(gib[2 * Hd + j] + r * ghb[2 * Hd + j]);
    h[i] = (1.0f - z) * n + z * h[i];
}

__global__ __launch_bounds__(256) void init_hh_tok(
    const float* __restrict__ h_f, const float* __restrict__ h_b,
    const int* __restrict__ tgt, float* __restrict__ hh, int* __restrict__ tok)
{
    int i = blockIdx.x * blockDim.x + threadIdx.x;
    int b = i >> 11, j = i & 2047;
    hh[i] = (j < H) ? h_f[(size_t)b * H + j] : h_b[(size_t)b * H + (j - H)];
    if (j == 0) tok[b] = tgt[b * T];
}

// ===========================================================================
extern "C" void kernel_launch(void* const* d_in, const int* in_sizes, int n_in,
                              void* d_out, int out_size, void* d_ws, size_t ws_size,
                              hipStream_t stream)
{
    const int*   src     = (const int*)d_in[0];
    const int*   tgt     = (const int*)d_in[1];
    const float* enc_emb = (const float*)d_in[2];
    const float* dec_emb = (const float*)d_in[3];
    const float* W_ih_f  = (const float*)d_in[4];
    const float* W_hh_f  = (const float*)d_in[5];
    const float* b_ih_f  = (const float*)d_in[6];
    const float* b_hh_f  = (const float*)d_in[7];
    const float* W_ih_b  = (const float*)d_in[8];
    const float* W_hh_b  = (const float*)d_in[9];
    const float* b_ih_b  = (const float*)d_in[10];
    const float* b_hh_b  = (const float*)d_in[11];
    const float* W_ih_d  = (const float*)d_in[12];
    const float* W_hh_d  = (const float*)d_in[13];
    const float* b_ih_d  = (const float*)d_in[14];
    const float* b_hh_d  = (const float*)d_in[15];
    const float* W_fc    = (const float*)d_in[16];
    const float* b_fc    = (const float*)d_in[17];
    float* out = (float*)d_out;

    // ---------------- workspace layout ----------------
    char* base = (char*)d_ws;
    size_t off = 0;
    auto alloc = [&](size_t bytes) { char* p = base + off; off += (bytes + 255) & ~(size_t)255; return p; };

    float*   hE     = (float*)  alloc((size_t)2 * B * H * 4);       // zeroed with AfrEA
    ushortT* AfrEA  = (ushortT*)alloc((size_t)2 * B * H * 2 * 2);   // enc A planes ping
    ushortT* AfrEB  = (ushortT*)alloc((size_t)2 * B * H * 2 * 2);   // enc A planes pong
    float*   hh     = (float*)  alloc((size_t)B * H2 * 4);
    ushortT* AfrDA  = (ushortT*)alloc((size_t)B * H2 * 2 * 2);      // dec A planes ping
    ushortT* AfrDB  = (ushortT*)alloc((size_t)B * H2 * 2 * 2);      // dec A planes pong
    float*   giTabF = (float*)  alloc((size_t)VOUTD * H3 * 4);
    float*   giTabB = (float*)  alloc((size_t)VOUTD * H3 * 4);
    float*   giTabD = (float*)  alloc((size_t)VOUTD * H6 * 4);
    float*   giPart = (float*)  alloc((size_t)4 * VOUTD * H6 * 4);  // split-K partials
    ushortT* WfrF   = (ushortT*)alloc((size_t)H3 * H * 2 * 2);
    ushortT* WfrB   = (ushortT*)alloc((size_t)H3 * H * 2 * 2);
    ushortT* WfrD   = (ushortT*)alloc((size_t)H6 * H2 * 2 * 2);
    int*     tok    = (int*)    alloc((size_t)B * 4);
    size_t required = off;

    dim3 blk(256);

    if (ws_size >= required) {
        // =================== fragment-major fused path ===================
        {   // zero hE fp32 + AfrEA (contiguous)
            size_t zbytes = (size_t)2 * B * H * 4 + (size_t)2 * B * H * 4;
            int n16 = (int)(zbytes / 16);
            zero16<<<dim3((n16 + 255) / 256), blk, 0, stream>>>((uint4*)hE, n16);
        }
        // W -> fragment-major hi/lo (coalesced, wave per fragment)
        {
            int fe = (H / 16) * (H / 32) * 3;        // 6144
            int fd = (H2 / 16) * (H2 / 32) * 3;      // 24576
            swizzle_w<<<dim3((fe + 3) / 4), blk, 0, stream>>>(W_hh_f, WfrF, 10, 7);
            swizzle_w<<<dim3((fe + 3) / 4), blk, 0, stream>>>(W_hh_b, WfrB, 10, 7);
            swizzle_w<<<dim3((fd + 3) / 4), blk, 0, stream>>>(W_hh_d, WfrD, 11, 8);
        }

        // gi tables (exact fp32, split-K x4)
        gemm_sk<<<dim3(H3 / 64, VOUTD / 64, 4), blk, 0, stream>>>(
            enc_emb, E, W_ih_f, giPart, H3, E, 4);
        gi_combine<<<dim3(H3 / 256, VOUTD), blk, 0, stream>>>(giPart, b_ih_f, giTabF, H3, 4);
        gemm_sk<<<dim3(H3 / 64, VOUTD / 64, 4), blk, 0, stream>>>(
            enc_emb, E, W_ih_b, giPart, H3, E, 4);
        gi_combine<<<dim3(H3 / 256, VOUTD), blk, 0, stream>>>(giPart, b_ih_b, giTabB, H3, 4);
        gemm_sk<<<dim3(H6 / 64, VOUTD / 64, 4), blk, 0, stream>>>(
            dec_emb, E, W_ih_d, giPart, H6, E, 4);
        gi_combine<<<dim3(H6 / 256, VOUTD), blk, 0, stream>>>(giPart, b_ih_d, giTabD, H6, 4);

        // ---------------- Encoder: 64 fused steps ----------------
        for (int s = 0; s < S; ++s) {
            const ushortT* inA = (s & 1) ? AfrEB : AfrEA;
            ushortT* outA = (s & 1) ? AfrEA : AfrEB;
            fused_step_enc<<<dim3(256), blk, 0, stream>>>(
                inA, WfrF, WfrB, giTabF, giTabB, src, s, b_hh_f, b_hh_b, hE, outA);
        }

        init_hh_tok_split<<<dim3((B * H2) / 256), blk, 0, stream>>>(
            hE, hE + (size_t)B * H, tgt, hh, AfrDA, tok);

        // ---------------- Decoder: 31 fused steps ----------------
        for (int t = 0; t < T - 1; ++t) {
            const ushortT* inA = (t & 1) ? AfrDB : AfrDA;
            ushortT* outA = (t & 1) ? AfrDA : AfrDB;
            fused_step_dec<<<dim3(256), blk, 0, stream>>>(
                inA, WfrD, giTabD, tok, b_hh_d, hh, outA);
            logits_argmax2<<<dim3(B / 2), blk, 0, stream>>>(hh, W_fc, b_fc, out, tok, t);
        }
    } else {
        // =================== fp32 fallback (R1-proven path) ===================
        {
            size_t zbytes = (size_t)2 * B * H * 4;
            int n16 = (int)(zbytes / 16);
            zero16<<<dim3((n16 + 255) / 256), blk, 0, stream>>>((uint4*)hE, n16);
        }
        float* giE = (float*)WfrF;                       // scratch overlay
        float* ghF = giE + (size_t)2 * B * H3;
        dim3 grid_gi(H3 / 64, (2 * B) / 64);
        dim3 grid_gate((2 * B * H) / 256);
        for (int s = 0; s < S; ++s) {
            gemm_enc<<<grid_gi, blk, 0, stream>>>(enc_emb, E, E, src, s,
                                                  W_ih_f, b_ih_f, W_ih_b, b_ih_b, giE, H3);
            gemm_enc<<<grid_gi, blk, 0, stream>>>(hE, H, H, nullptr, 0,
                                                  W_hh_f, b_hh_f, W_hh_b, b_hh_b, ghF, H3);
            gru_gate<<<grid_gate, blk, 0, stream>>>(giE, ghF, hE, H);
        }
        init_hh_tok<<<dim3((B * H2) / 256), blk, 0, stream>>>(hE, hE + (size_t)B * H, tgt, hh, tok);
        dim3 grid_d(H6 / 64, B / 64);
        dim3 grid_dgate((B * H2) / 256);
        for (int t = 0; t < T - 1; ++t) {
            gemm_bias<<<grid_d, blk, 0, stream>>>(dec_emb, tok, 1, 0, E,
                                                  W_ih_d, b_ih_d, giE, H6, E);
            gemm_bias<<<grid_d, blk, 0, stream>>>(hh, nullptr, 0, 0, H2,
                                                  W_hh_d, b_hh_d, ghF, H6, H2);
            gru_gate<<<grid_dgate, blk, 0, stream>>>(giE, ghF, hh, H2);
            logits_argmax2<<<dim3(B / 2), blk, 0, stream>>>(hh, W_fc, b_fc, out, tok, t);
        }
    }
}

// Round 10
// 4615.590 us; speedup vs baseline: 1.2121x; 1.0410x over previous
//
#include <hip/hip_runtime.h>
#include <math.h>

#define B 512
#define S 64
#define T 32
#define E 512
#define H 1024
#define VOUTD 128
#define H2 (2*H)
#define H3 (3*H)
#define H6 (6*H)

typedef unsigned short ushortT;
typedef unsigned int uintT;
typedef __attribute__((ext_vector_type(8))) short short8;
typedef __attribute__((ext_vector_type(4))) float floatx4;

__device__ __forceinline__ float sigmoidf_(float x) { return 1.0f / (1.0f + expf(-x)); }

__device__ __forceinline__ uintT pack_hi2(float a, float b) {
    return (__float_as_uint(a) >> 16) | (__float_as_uint(b) & 0xFFFF0000u);
}
__device__ __forceinline__ uintT pack_lo2(float a, float b) {
    uintT ua = __float_as_uint(a), ub = __float_as_uint(b);
    uintT la = __float_as_uint(a - __uint_as_float(ua & 0xFFFF0000u)) >> 16;
    uintT lb = __float_as_uint(b - __uint_as_float(ub & 0xFFFF0000u)) >> 16;
    return la | (lb << 16);
}

__global__ __launch_bounds__(256) void zero16(uint4* __restrict__ p, int n)
{
    int i = blockIdx.x * 256 + threadIdx.x;
    if (i < n) p[i] = make_uint4(0u, 0u, 0u, 0u);
}

// ===========================================================================
// W -> fragment-major hi/lo planes. COALESCED: one wave per fragment.
// Fragment f = (jb*ncK + c)*3 + g; 1024 shorts (hi 512 | lo 512).
// ncK = K/32 = 1 << (kShift-2)  =>  jb = rest >> (kShift-2).
// ===========================================================================
__global__ __launch_bounds__(256) void swizzle_w(
    const float* __restrict__ W, ushortT* __restrict__ out, int njShift, int kShift)
{
    const int K = 8 << kShift;
    const int nj = 1 << njShift;
    const int ncK = K >> 5;
    const int total = (nj >> 4) * ncK * 3;
    int f = blockIdx.x * 4 + (threadIdx.x >> 6);
    if (f >= total) return;
    const int lane = threadIdx.x & 63;
    int g = f % 3;
    int rest = f / 3;
    int c = rest & (ncK - 1);
    int jb = rest >> (kShift - 2);
    int jl = lane & 15, kq = lane >> 4;
    int row = g * nj + jb * 16 + jl;
    int k = c * 32 + kq * 8;
    const float* s = W + (size_t)row * K + k;
    float4 f0 = *(const float4*)s;
    float4 f1 = *(const float4*)(s + 4);
    uint4 hv = make_uint4(pack_hi2(f0.x, f0.y), pack_hi2(f0.z, f0.w),
                          pack_hi2(f1.x, f1.y), pack_hi2(f1.z, f1.w));
    uint4 lv = make_uint4(pack_lo2(f0.x, f0.y), pack_lo2(f0.z, f0.w),
                          pack_lo2(f1.x, f1.y), pack_lo2(f1.z, f1.w));
    size_t base = (size_t)f * 1024 + (size_t)lane * 8;
    *(uint4*)(out + base) = hv;
    *(uint4*)(out + base + 512) = lv;
}

// ===========================================================================
// Barrier-free streaming main loop (R9 tile) + IN-BLOCK SPLIT-K:
// block = 512 thr = 8 waves = 4 row-stacked (wr) x 2 K-halves (kh), covering
// 256 rows x 16 j. Each wave streams its K-half global->register with the
// 2-deep ping-pong; kh=1 dumps acc to LDS, one barrier, kh=0 adds partials
// (acc_low + acc_high, deterministic) and runs the fused gate. 2048 waves
// total = 2 waves/SIMD (vs R9's 1) at identical operand traffic.
// Per-acc MFMA order within a K-half: Ah*Bh, Ah*Bl, Al*Bh; chunks ascending.
// ===========================================================================
#define MFMA16(a, b, c) __builtin_amdgcn_mfma_f32_16x16x32_bf16(a, b, c, 0, 0, 0)

#define LOADSET(SET, C)                                                         \
    {                                                                           \
        const ushortT* bp_ = bPtr + (size_t)(C) * 3072;                         \
        SET##b[0] = *(const short8*)(bp_);                                      \
        SET##b[1] = *(const short8*)(bp_ + 512);                                \
        SET##b[2] = *(const short8*)(bp_ + 1024);                               \
        SET##b[3] = *(const short8*)(bp_ + 1536);                               \
        SET##b[4] = *(const short8*)(bp_ + 2048);                               \
        SET##b[5] = *(const short8*)(bp_ + 2560);                               \
        _Pragma("unroll")                                                       \
        for (int rb_ = 0; rb_ < 4; ++rb_) {                                     \
            const ushortT* ap_ = aPtr + (size_t)rb_ * (NCKd * 1024)             \
                                      + (size_t)(C) * 1024;                     \
            SET##a[rb_ * 2]     = *(const short8*)(ap_);                        \
            SET##a[rb_ * 2 + 1] = *(const short8*)(ap_ + 512);                  \
        }                                                                       \
    }

#define COMPSET(SET)                                                            \
    _Pragma("unroll")                                                           \
    for (int g = 0; g < 3; ++g) {                                               \
        short8 bh_ = SET##b[g * 2], bl_ = SET##b[g * 2 + 1];                    \
        _Pragma("unroll")                                                       \
        for (int mi = 0; mi < 4; ++mi) {                                        \
            acc[mi][g] = MFMA16(SET##a[mi * 2], bh_, acc[mi][g]);               \
            acc[mi][g] = MFMA16(SET##a[mi * 2], bl_, acc[mi][g]);               \
            acc[mi][g] = MFMA16(SET##a[mi * 2 + 1], bh_, acc[mi][g]);           \
        }                                                                       \
    }

#define MAIN_LOOP()                                                             \
    LOADSET(s0, 0);                                                             \
    for (int c = 0; c < NCKh; c += 2) {                                         \
        LOADSET(s1, c + 1);                                                     \
        COMPSET(s0);                                                            \
        if (c + 2 < NCKh) LOADSET(s0, c + 2);                                   \
        COMPSET(s1);                                                            \
    }

// Split-K combine: kh=1 waves write 12 floatx4/lane to LDS (conflict-free
// b128), barrier, kh=0 adds.
#define SPLITK_COMBINE()                                                        \
    if (kh == 1) {                                                              \
        _Pragma("unroll")                                                       \
        for (int mi = 0; mi < 4; ++mi)                                          \
            _Pragma("unroll")                                                   \
            for (int g = 0; g < 3; ++g) part[wr][mi * 3 + g][lane] = acc[mi][g];\
    }                                                                           \
    __syncthreads();                                                            \
    if (kh == 0) {                                                              \
        _Pragma("unroll")                                                       \
        for (int mi = 0; mi < 4; ++mi)                                          \
            _Pragma("unroll")                                                   \
            for (int g = 0; g < 3; ++g) acc[mi][g] = acc[mi][g] + part[wr][mi * 3 + g][lane]; \
    }

// Coalesced A-plane store: 32 runs (16 rb x 2 planes) x 256 shorts; 512 thr,
// 32B each (2 uint4).
#define EPILOGUE_STORE512(NCKA)                                                 \
    __syncthreads();                                                            \
    {                                                                           \
        const int run = t >> 4;            /* 0..31 */                          \
        const int rb_ = run >> 1;          /* 0..15 */                          \
        const int pl_ = run & 1;           /* hi/lo */                          \
        const int sub = t & 15;                                                 \
        const ushortT* sp = &eb[rb_][pl_ * 256 + sub * 16];                     \
        ushortT* dp = AfrOut + (((size_t)((m0 >> 4) + rb_)) * (NCKA) + cA) * 1024 \
                    + pl_ * 512 + kqpar * 256 + sub * 16;                       \
        *(uint4*)(dp)     = *(const uint4*)(sp);                                \
        *(uint4*)(dp + 8) = *(const uint4*)(sp + 8);                            \
    }

// ===========================================================================
// FUSED encoder step. Block = 256 rows x 16 j, 8 waves (4 wr x 2 kh).
// Grid 256 = 8 xcd x (8 jg16-offsets x 4 mb).
// ===========================================================================
__global__ __launch_bounds__(512, 2) void fused_step_enc(
    const ushortT* __restrict__ Afr,
    const ushortT* __restrict__ WfrF, const ushortT* __restrict__ WfrB,
    const float* __restrict__ giTabF, const float* __restrict__ giTabB,
    const int* __restrict__ src, int s,
    const float* __restrict__ bhF, const float* __restrict__ bhB,
    float* __restrict__ h, ushortT* __restrict__ AfrOut)
{
    __shared__ floatx4 part[4][12][64];   // 48 KB split-K partials
    __shared__ ushortT eb[16][512];       // 16 KB epilogue staging
    const int t = threadIdx.x, lane = t & 63, w = t >> 6;
    const int wr = w & 3, kh = w >> 2;
    const int bid = blockIdx.x;
    const int xcd = bid & 7, q = bid >> 3;
    const int jg16 = xcd * 8 + (q & 7);   // [0,64)
    const int mb   = q >> 3;              // [0,4)
    const int j0 = jg16 * 16, m0 = mb * 256;
    const bool bwd = (m0 >= B);
    const ushortT* Wfr = bwd ? WfrB : WfrF;
    const float* giTab = bwd ? giTabB : giTabF;
    const float* bh = bwd ? bhB : bhF;
    const int NCKd = 32, NCKh = 16;
    const int sidx = bwd ? (S - 1 - s) : s;

    const ushortT* aPtr = Afr + (size_t)((m0 >> 4) + wr * 4) * (NCKd * 1024)
                        + (size_t)kh * NCKh * 1024 + lane * 8;
    const ushortT* bPtr = Wfr + (size_t)jg16 * (NCKd * 3072)
                        + (size_t)kh * NCKh * 3072 + lane * 8;

    floatx4 acc[4][3];
#pragma unroll
    for (int mi = 0; mi < 4; ++mi)
#pragma unroll
        for (int g = 0; g < 3; ++g) acc[mi][g] = (floatx4){0.f, 0.f, 0.f, 0.f};

    short8 s0b[6], s0a[8], s1b[6], s1a[8];
    MAIN_LOOP();
    SPLITK_COMBINE();

    // fused gate epilogue (kh=0 waves only; 4 waves cover 256 rows)
    const int cA = jg16 >> 1;
    const int kqpar = jg16 & 1;
    if (kh == 0) {
        const int colj = j0 + (lane & 15);
        const float bR = bh[colj], bZ = bh[H + colj], bN = bh[2 * H + colj];
        const int khalf = (lane >> 3) & 1;
        const int e7 = lane & 7;
#pragma unroll
        for (int mi = 0; mi < 4; ++mi) {
#pragma unroll
            for (int r = 0; r < 4; ++r) {
                const int r15 = (lane >> 4) * 4 + r;
                const int row = m0 + wr * 64 + mi * 16 + r15;
                const int tk = src[(row & (B - 1)) * S + sidx];
                const float* gi = giTab + (size_t)tk * H3;
                float ghr = acc[mi][0][r] + bR;
                float ghz = acc[mi][1][r] + bZ;
                float ghn = acc[mi][2][r] + bN;
                float rr = sigmoidf_(gi[colj] + ghr);
                float z  = sigmoidf_(gi[H + colj] + ghz);
                float n  = tanhf(gi[2 * H + colj] + rr * ghn);
                const size_t idx = (size_t)row * H + colj;
                float hnew = (1.0f - z) * n + z * h[idx];
                h[idx] = hnew;
                uintT u = __float_as_uint(hnew);
                const int slot = (r15 + 16 * khalf) * 8 + e7;
                eb[wr * 4 + mi][slot] = (ushortT)(u >> 16);
                eb[wr * 4 + mi][256 + slot] =
                    (ushortT)(__float_as_uint(hnew - __uint_as_float(u & 0xFFFF0000u)) >> 16);
            }
        }
    }
    EPILOGUE_STORE512(32)
}

// ===========================================================================
// FUSED decoder step: Hd = 2H, gates {j, 2H+j, 4H+j}. Same structure.
// Grid 256 = 8 xcd x (16 jg16-offsets x 2 mb).
// ===========================================================================
__global__ __launch_bounds__(512, 2) void fused_step_dec(
    const ushortT* __restrict__ Afr, const ushortT* __restrict__ Wfr,
    const float* __restrict__ giTabD, const int* __restrict__ tok,
    const float* __restrict__ bhD,
    float* __restrict__ h, ushortT* __restrict__ AfrOut)
{
    __shared__ floatx4 part[4][12][64];
    __shared__ ushortT eb[16][512];
    const int t = threadIdx.x, lane = t & 63, w = t >> 6;
    const int wr = w & 3, kh = w >> 2;
    const int bid = blockIdx.x;
    const int xcd = bid & 7, q = bid >> 3;
    const int jg16 = xcd * 16 + (q & 15); // [0,128)
    const int mb   = q >> 4;              // [0,2)
    const int j0 = jg16 * 16, m0 = mb * 256;
    const int NCKd = 64, NCKh = 32;

    const ushortT* aPtr = Afr + (size_t)((m0 >> 4) + wr * 4) * (NCKd * 1024)
                        + (size_t)kh * NCKh * 1024 + lane * 8;
    const ushortT* bPtr = Wfr + (size_t)jg16 * (NCKd * 3072)
                        + (size_t)kh * NCKh * 3072 + lane * 8;

    floatx4 acc[4][3];
#pragma unroll
    for (int mi = 0; mi < 4; ++mi)
#pragma unroll
        for (int g = 0; g < 3; ++g) acc[mi][g] = (floatx4){0.f, 0.f, 0.f, 0.f};

    short8 s0b[6], s0a[8], s1b[6], s1a[8];
    MAIN_LOOP();
    SPLITK_COMBINE();

    const int cA = jg16 >> 1;
    const int kqpar = jg16 & 1;
    if (kh == 0) {
        const int colj = j0 + (lane & 15);
        const float bR = bhD[colj], bZ = bhD[H2 + colj], bN = bhD[2 * H2 + colj];
        const int khalf = (lane >> 3) & 1;
        const int e7 = lane & 7;
#pragma unroll
        for (int mi = 0; mi < 4; ++mi) {
#pragma unroll
            for (int r = 0; r < 4; ++r) {
                const int r15 = (lane >> 4) * 4 + r;
                const int row = m0 + wr * 64 + mi * 16 + r15;
                const float* gi = giTabD + (size_t)tok[row] * H6;
                float ghr = acc[mi][0][r] + bR;
                float ghz = acc[mi][1][r] + bZ;
                float ghn = acc[mi][2][r] + bN;
                float rr = sigmoidf_(gi[colj] + ghr);
                float z  = sigmoidf_(gi[H2 + colj] + ghz);
                float n  = tanhf(gi[2 * H2 + colj] + rr * ghn);
                const size_t idx = (size_t)row * H2 + colj;
                float hnew = (1.0f - z) * n + z * h[idx];
                h[idx] = hnew;
                uintT u = __float_as_uint(hnew);
                const int slot = (r15 + 16 * khalf) * 8 + e7;
                eb[wr * 4 + mi][slot] = (ushortT)(u >> 16);
                eb[wr * 4 + mi][256 + slot] =
                    (ushortT)(__float_as_uint(hnew - __uint_as_float(u & 0xFFFF0000u)) >> 16);
            }
        }
    }
    EPILOGUE_STORE512(64)
}

// hh fp32 row-major + dec A planes (fragment-major); tok[b]=tgt[b,0]
__global__ __launch_bounds__(256) void init_hh_tok_split(
    const float* __restrict__ h_f, const float* __restrict__ h_b,
    const int* __restrict__ tgt, float* __restrict__ hh,
    ushortT* __restrict__ AfrD, int* __restrict__ tok)
{
    int i = blockIdx.x * blockDim.x + threadIdx.x;   // over B*2H
    int b = i >> 11;
    int j = i & 2047;
    float v = (j < H) ? h_f[(size_t)b * H + j] : h_b[(size_t)b * H + (j - H)];
    hh[i] = v;
    uintT u = __float_as_uint(v);
    size_t ao = (((size_t)(b >> 4) * 64 + (j >> 5)) * 2) * 512
              + (size_t)((b & 15) + 16 * ((j >> 3) & 3)) * 8 + (j & 7);
    AfrD[ao] = (ushortT)(u >> 16);
    AfrD[ao + 512] = (ushortT)(__float_as_uint(v - __uint_as_float(u & 0xFFFF0000u)) >> 16);
    if (j == 0) tok[b] = tgt[b * T];
}

// ===========================================================================
// logits = hh @ W_fc^T + b_fc (V=128) + argmax; 2 rows/block, 256 thr.
// ===========================================================================
__global__ __launch_bounds__(256) void logits_argmax2(
    const float* __restrict__ hh, const float* __restrict__ W_fc,
    const float* __restrict__ b_fc, float* __restrict__ out,
    int* __restrict__ tok, int t)
{
    __shared__ float sh[2][H2];
    __shared__ float sred[2][2][128];
    __shared__ float sval[2][128];
    __shared__ int   sidx[2][128];
    const int tid = threadIdx.x;
    const int col = tid & 127;
    const int kh  = tid >> 7;
    const int b0  = blockIdx.x * 2;

    {
        const float4* srcp = (const float4*)(hh + (size_t)b0 * H2);
        float4* dst = (float4*)sh;
        for (int i = tid; i < 2 * H2 / 4; i += 256) dst[i] = srcp[i];
    }
    __syncthreads();

    const float* wrow = W_fc + (size_t)col * H2 + kh * (H2 / 2);
    const float* s0 = sh[0] + kh * (H2 / 2);
    const float* s1 = sh[1] + kh * (H2 / 2);
    float a0 = 0.f, a1 = 0.f;
#pragma unroll 8
    for (int k = 0; k < H2 / 2; k += 4) {
        float4 w4 = *(const float4*)(wrow + k);
        float4 h0 = *(const float4*)(s0 + k);
        float4 h1 = *(const float4*)(s1 + k);
        a0 += w4.x * h0.x + w4.y * h0.y + w4.z * h0.z + w4.w * h0.w;
        a1 += w4.x * h1.x + w4.y * h1.y + w4.z * h1.z + w4.w * h1.w;
    }
    sred[kh][0][col] = a0;
    sred[kh][1][col] = a1;
    __syncthreads();

    if (kh == 0) {
        float l0 = sred[0][0][col] + sred[1][0][col] + b_fc[col];
        float l1 = sred[0][1][col] + sred[1][1][col] + b_fc[col];
        out[(size_t)(b0 + 0) * ((T - 1) * VOUTD) + (size_t)t * VOUTD + col] = l0;
        out[(size_t)(b0 + 1) * ((T - 1) * VOUTD) + (size_t)t * VOUTD + col] = l1;
        sval[0][col] = l0; sidx[0][col] = col;
        sval[1][col] = l1; sidx[1][col] = col;
    }
    __syncthreads();

    const int r = tid >> 7, c = tid & 127;
    for (int off = 64; off > 0; off >>= 1) {
        if (c < off) {
            float ov = sval[r][c + off]; int oi = sidx[r][c + off];
            if (ov > sval[r][c] || (ov == sval[r][c] && oi < sidx[r][c])) {
                sval[r][c] = ov; sidx[r][c] = oi;
            }
        }
        __syncthreads();
    }
    if (tid < 2) tok[b0 + tid] = sidx[tid][0];
}

// ===========================================================================
// Split-K fp32 GEMM (exact) + deterministic combine (gi tables).
// ===========================================================================
__global__ __launch_bounds__(256) void gemm_sk(
    const float* __restrict__ Abase, int lda,
    const float* __restrict__ W, float* __restrict__ Cp, int N, int K, int KS)
{
    __shared__ float As[16][68];
    __shared__ float Ws[16][68];
    const int t = threadIdx.x;
    const int m0 = blockIdx.y * 64, n0 = blockIdx.x * 64;
    const int Kc = K / KS, kb = blockIdx.z * Kc;
    const int lr = t >> 2, lc = (t & 3) << 2;
    const int tx = t & 15, ty = t >> 4;
    const int tn0 = tx << 2, tm0 = ty << 2;
    const float* Aptr = Abase + (size_t)(m0 + lr) * lda + kb;
    const float* Wptr = W + (size_t)(n0 + lr) * K + kb;
    float acc[4][4] = {{0.f}};
    for (int k0 = 0; k0 < Kc; k0 += 16) {
        float4 a4 = *(const float4*)(Aptr + k0 + lc);
        float4 w4 = *(const float4*)(Wptr + k0 + lc);
        __syncthreads();
        As[lc+0][lr] = a4.x; As[lc+1][lr] = a4.y; As[lc+2][lr] = a4.z; As[lc+3][lr] = a4.w;
        Ws[lc+0][lr] = w4.x; Ws[lc+1][lr] = w4.y; Ws[lc+2][lr] = w4.z; Ws[lc+3][lr] = w4.w;
        __syncthreads();
#pragma unroll
        for (int kk = 0; kk < 16; ++kk) {
            float4 av = *(const float4*)&As[kk][tm0];
            float4 wv = *(const float4*)&Ws[kk][tn0];
            float am[4] = {av.x, av.y, av.z, av.w};
            float wn[4] = {wv.x, wv.y, wv.z, wv.w};
#pragma unroll
            for (int i = 0; i < 4; ++i)
#pragma unroll
                for (int j = 0; j < 4; ++j) acc[i][j] += am[i] * wn[j];
        }
    }
    float* Cb = Cp + ((size_t)blockIdx.z * VOUTD + m0 + tm0) * N + n0 + tn0;
#pragma unroll
    for (int i = 0; i < 4; ++i)
        *(float4*)(Cb + (size_t)i * N) = make_float4(acc[i][0], acc[i][1], acc[i][2], acc[i][3]);
}

__global__ __launch_bounds__(256) void gi_combine(
    const float* __restrict__ Cp, const float* __restrict__ bias,
    float* __restrict__ Cout, int N, int KS)
{
    int j = blockIdx.x * 256 + threadIdx.x;
    int v = blockIdx.y;
    float s = 0.f;
    for (int z = 0; z < KS; ++z) s += Cp[((size_t)z * VOUTD + v) * N + j];
    Cout[(size_t)v * N + j] = s + bias[j];
}

// ===========================================================================
// fp32 vector GEMM (fallback path only).
// ===========================================================================
__global__ __launch_bounds__(256) void gemm_bias(
    const float* __restrict__ Abase,
    const int* __restrict__ idx, int idxStride, int idxOff, int lda,
    const float* __restrict__ W, const float* __restrict__ bias,
    float* __restrict__ C, int N, int K)
{
    __shared__ float As[16][68];
    __shared__ float Ws[16][68];
    const int t = threadIdx.x;
    const int m0 = blockIdx.y * 64, n0 = blockIdx.x * 64;
    const int lr = t >> 2, lc = (t & 3) << 2;
    const int tx = t & 15, ty = t >> 4;
    const int tn0 = tx << 2, tm0 = ty << 2;
    const int arow = m0 + lr;
    const float* Aptr = idx ? (Abase + (size_t)idx[arow * idxStride + idxOff] * lda)
                            : (Abase + (size_t)arow * lda);
    const float* Wptr = W + (size_t)(n0 + lr) * K;
    float acc[4][4] = {{0.f}};
    for (int k0 = 0; k0 < K; k0 += 16) {
        float4 a4 = *(const float4*)(Aptr + k0 + lc);
        float4 w4 = *(const float4*)(Wptr + k0 + lc);
        __syncthreads();
        As[lc+0][lr] = a4.x; As[lc+1][lr] = a4.y; As[lc+2][lr] = a4.z; As[lc+3][lr] = a4.w;
        Ws[lc+0][lr] = w4.x; Ws[lc+1][lr] = w4.y; Ws[lc+2][lr] = w4.z; Ws[lc+3][lr] = w4.w;
        __syncthreads();
#pragma unroll
        for (int kk = 0; kk < 16; ++kk) {
            float4 av = *(const float4*)&As[kk][tm0];
            float4 wv = *(const float4*)&Ws[kk][tn0];
            float am[4] = {av.x, av.y, av.z, av.w};
            float wn[4] = {wv.x, wv.y, wv.z, wv.w};
#pragma unroll
            for (int i = 0; i < 4; ++i)
#pragma unroll
                for (int j = 0; j < 4; ++j) acc[i][j] += am[i] * wn[j];
        }
    }
    const float b0 = bias[n0+tn0], b1 = bias[n0+tn0+1], b2 = bias[n0+tn0+2], b3 = bias[n0+tn0+3];
#pragma unroll
    for (int i = 0; i < 4; ++i) {
        float4 o = make_float4(acc[i][0]+b0, acc[i][1]+b1, acc[i][2]+b2, acc[i][3]+b3);
        *(float4*)(C + (size_t)(m0 + tm0 + i) * N + n0 + tn0) = o;
    }
}

__global__ __launch_bounds__(256) void gemm_enc(
    const float* __restrict__ Abase, int lda, int K,
    const int* __restrict__ srcIdx, int s,
    const float* __restrict__ W1, const float* __restrict__ bias1,
    const float* __restrict__ W2, const float* __restrict__ bias2,
    float* __restrict__ C, int N)
{
    __shared__ float As[16][68];
    __shared__ float Ws[16][68];
    const int t = threadIdx.x;
    const int m0 = blockIdx.y * 64, n0 = blockIdx.x * 64;
    const bool bwd = (m0 >= B);
    const float* W = bwd ? W2 : W1;
    const float* bias = bwd ? bias2 : bias1;
    const int lr = t >> 2, lc = (t & 3) << 2;
    const int tx = t & 15, ty = t >> 4;
    const int tn0 = tx << 2, tm0 = ty << 2;
    const int arow = m0 + lr;
    const float* Aptr;
    if (srcIdx) {
        int r = arow & (B - 1);
        int sidx = bwd ? (S - 1 - s) : s;
        Aptr = Abase + (size_t)srcIdx[r * S + sidx] * lda;
    } else Aptr = Abase + (size_t)arow * lda;
    const float* Wptr = W + (size_t)(n0 + lr) * K;
    float acc[4][4] = {{0.f}};
    for (int k0 = 0; k0 < K; k0 += 16) {
        float4 a4 = *(const float4*)(Aptr + k0 + lc);
        float4 w4 = *(const float4*)(Wptr + k0 + lc);
        __syncthreads();
        As[lc+0][lr] = a4.x; As[lc+1][lr] = a4.y; As[lc+2][lr] = a4.z; As[lc+3][lr] = a4.w;
        Ws[lc+0][lr] = w4.x; Ws[lc+1][lr] = w4.y; Ws[lc+2][lr] = w4.z; Ws[lc+3][lr] = w4.w;
        __syncthreads();
#pragma unroll
        for (int kk = 0; kk < 16; ++kk) {
            float4 av = *(const float4*)&As[kk][tm0];
            float4 wv = *(const float4*)&Ws[kk][tn0];
            float am[4] = {av.x, av.y, av.z, av.w};
            float wn[4] = {wv.x, wv.y, wv.z, wv.w};
#pragma unroll
            for (int i = 0; i < 4; ++i)
#pragma unroll
                for (int j = 0; j < 4; ++j) acc[i][j] += am[i] * wn[j];
        }
    }
    const float b0 = bias[n0+tn0], b1 = bias[n0+tn0+1], b2 = bias[n0+tn0+2], b3 = bias[n0+tn0+3];
#pragma unroll
    for (int i = 0; i < 4; ++i) {
        float4 o = make_float4(acc[i][0]+b0, acc[i][1]+b1, acc[i][2]+b2, acc[i][3]+b3);
        *(float4*)(C + (size_t)(m0 + tm0 + i) * N + n0 + tn0) = o;
    }
}

__global__ __launch_bounds__(256) void gru_gate(
    const float* __restrict__ gi, const float* __restrict__ gh,
    float* __restrict__ h, int Hd)
{
    int i = blockIdx.x * blockDim.x + threadIdx.x;
    int b = i / Hd, j = i - b * Hd;
    const float* gib = gi + (size_t)b * 3 * Hd;
    const float* ghb = gh + (size_t)b * 3 * Hd;
    float r = sigmoidf_(gib[j] + ghb[j]);
    float z = sigmoidf_(gib[Hd + j] + ghb[Hd + j]);
    float n = tanhf(gib[2 * Hd + j] + r * ghb[2 * Hd + j]);
    h[i] = (1.0f - z) * n + z * h[i];
}

__global__ __launch_bounds__(256) void init_hh_tok(
    const float* __restrict__ h_f, const float* __restrict__ h_b,
    const int* __restrict__ tgt, float* __restrict__ hh, int* __restrict__ tok)
{
    int i = blockIdx.x * blockDim.x + threadIdx.x;
    int b = i >> 11, j = i & 2047;
    hh[i] = (j < H) ? h_f[(size_t)b * H + j] : h_b[(size_t)b * H + (j - H)];
    if (j == 0) tok[b] = tgt[b * T];
}

// ===========================================================================
extern "C" void kernel_launch(void* const* d_in, const int* in_sizes, int n_in,
                              void* d_out, int out_size, void* d_ws, size_t ws_size,
                              hipStream_t stream)
{
    const int*   src     = (const int*)d_in[0];
    const int*   tgt     = (const int*)d_in[1];
    const float* enc_emb = (const float*)d_in[2];
    const float* dec_emb = (const float*)d_in[3];
    const float* W_ih_f  = (const float*)d_in[4];
    const float* W_hh_f  = (const float*)d_in[5];
    const float* b_ih_f  = (const float*)d_in[6];
    const float* b_hh_f  = (const float*)d_in[7];
    const float* W_ih_b  = (const float*)d_in[8];
    const float* W_hh_b  = (const float*)d_in[9];
    const float* b_ih_b  = (const float*)d_in[10];
    const float* b_hh_b  = (const float*)d_in[11];
    const float* W_ih_d  = (const float*)d_in[12];
    const float* W_hh_d  = (const float*)d_in[13];
    const float* b_ih_d  = (const float*)d_in[14];
    const float* b_hh_d  = (const float*)d_in[15];
    const float* W_fc    = (const float*)d_in[16];
    const float* b_fc    = (const float*)d_in[17];
    float* out = (float*)d_out;

    // ---------------- workspace layout ----------------
    char* base = (char*)d_ws;
    size_t off = 0;
    auto alloc = [&](size_t bytes) { char* p = base + off; off += (bytes + 255) & ~(size_t)255; return p; };

    float*   hE     = (float*)  alloc((size_t)2 * B * H * 4);       // zeroed with AfrEA
    ushortT* AfrEA  = (ushortT*)alloc((size_t)2 * B * H * 2 * 2);   // enc A planes ping
    ushortT* AfrEB  = (ushortT*)alloc((size_t)2 * B * H * 2 * 2);   // enc A planes pong
    float*   hh     = (float*)  alloc((size_t)B * H2 * 4);
    ushortT* AfrDA  = (ushortT*)alloc((size_t)B * H2 * 2 * 2);      // dec A planes ping
    ushortT* AfrDB  = (ushortT*)alloc((size_t)B * H2 * 2 * 2);      // dec A planes pong
    float*   giTabF = (float*)  alloc((size_t)VOUTD * H3 * 4);
    float*   giTabB = (float*)  alloc((size_t)VOUTD * H3 * 4);
    float*   giTabD = (float*)  alloc((size_t)VOUTD * H6 * 4);
    float*   giPart = (float*)  alloc((size_t)4 * VOUTD * H6 * 4);  // split-K partials
    ushortT* WfrF   = (ushortT*)alloc((size_t)H3 * H * 2 * 2);
    ushortT* WfrB   = (ushortT*)alloc((size_t)H3 * H * 2 * 2);
    ushortT* WfrD   = (ushortT*)alloc((size_t)H6 * H2 * 2 * 2);
    int*     tok    = (int*)    alloc((size_t)B * 4);
    size_t required = off;

    dim3 blk(256);
    dim3 blk512(512);

    if (ws_size >= required) {
        // =================== fragment-major fused path ===================
        {   // zero hE fp32 + AfrEA (contiguous)
            size_t zbytes = (size_t)2 * B * H * 4 + (size_t)2 * B * H * 4;
            int n16 = (int)(zbytes / 16);
            zero16<<<dim3((n16 + 255) / 256), blk, 0, stream>>>((uint4*)hE, n16);
        }
        // W -> fragment-major hi/lo (coalesced, wave per fragment)
        {
            int fe = (H / 16) * (H / 32) * 3;        // 6144
            int fd = (H2 / 16) * (H2 / 32) * 3;      // 24576
            swizzle_w<<<dim3((fe + 3) / 4), blk, 0, stream>>>(W_hh_f, WfrF, 10, 7);
            swizzle_w<<<dim3((fe + 3) / 4), blk, 0, stream>>>(W_hh_b, WfrB, 10, 7);
            swizzle_w<<<dim3((fd + 3) / 4), blk, 0, stream>>>(W_hh_d, WfrD, 11, 8);
        }

        // gi tables (exact fp32, split-K x4)
        gemm_sk<<<dim3(H3 / 64, VOUTD / 64, 4), blk, 0, stream>>>(
            enc_emb, E, W_ih_f, giPart, H3, E, 4);
        gi_combine<<<dim3(H3 / 256, VOUTD), blk, 0, stream>>>(giPart, b_ih_f, giTabF, H3, 4);
        gemm_sk<<<dim3(H3 / 64, VOUTD / 64, 4), blk, 0, stream>>>(
            enc_emb, E, W_ih_b, giPart, H3, E, 4);
        gi_combine<<<dim3(H3 / 256, VOUTD), blk, 0, stream>>>(giPart, b_ih_b, giTabB, H3, 4);
        gemm_sk<<<dim3(H6 / 64, VOUTD / 64, 4), blk, 0, stream>>>(
            dec_emb, E, W_ih_d, giPart, H6, E, 4);
        gi_combine<<<dim3(H6 / 256, VOUTD), blk, 0, stream>>>(giPart, b_ih_d, giTabD, H6, 4);

        // ---------------- Encoder: 64 fused steps ----------------
        for (int s = 0; s < S; ++s) {
            const ushortT* inA = (s & 1) ? AfrEB : AfrEA;
            ushortT* outA = (s & 1) ? AfrEA : AfrEB;
            fused_step_enc<<<dim3(256), blk512, 0, stream>>>(
                inA, WfrF, WfrB, giTabF, giTabB, src, s, b_hh_f, b_hh_b, hE, outA);
        }

        init_hh_tok_split<<<dim3((B * H2) / 256), blk, 0, stream>>>(
            hE, hE + (size_t)B * H, tgt, hh, AfrDA, tok);

        // ---------------- Decoder: 31 fused steps ----------------
        for (int t = 0; t < T - 1; ++t) {
            const ushortT* inA = (t & 1) ? AfrDB : AfrDA;
            ushortT* outA = (t & 1) ? AfrDA : AfrDB;
            fused_step_dec<<<dim3(256), blk512, 0, stream>>>(
                inA, WfrD, giTabD, tok, b_hh_d, hh, outA);
            logits_argmax2<<<dim3(B / 2), blk, 0, stream>>>(hh, W_fc, b_fc, out, tok, t);
        }
    } else {
        // =================== fp32 fallback (R1-proven path) ===================
        {
            size_t zbytes = (size_t)2 * B * H * 4;
            int n16 = (int)(zbytes / 16);
            zero16<<<dim3((n16 + 255) / 256), blk, 0, stream>>>((uint4*)hE, n16);
        }
        float* giE = (float*)WfrF;                       // scratch overlay
        float* ghF = giE + (size_t)2 * B * H3;
        dim3 grid_gi(H3 / 64, (2 * B) / 64);
        dim3 grid_gate((2 * B * H) / 256);
        for (int s = 0; s < S; ++s) {
            gemm_enc<<<grid_gi, blk, 0, stream>>>(enc_emb, E, E, src, s,
                                                  W_ih_f, b_ih_f, W_ih_b, b_ih_b, giE, H3);
            gemm_enc<<<grid_gi, blk, 0, stream>>>(hE, H, H, nullptr, 0,
                                                  W_hh_f, b_hh_f, W_hh_b, b_hh_b, ghF, H3);
            gru_gate<<<grid_gate, blk, 0, stream>>>(giE, ghF, hE, H);
        }
        init_hh_tok<<<dim3((B * H2) / 256), blk, 0, stream>>>(hE, hE + (size_t)B * H, tgt, hh, tok);
        dim3 grid_d(H6 / 64, B / 64);
        dim3 grid_dgate((B * H2) / 256);
        for (int t = 0; t < T - 1; ++t) {
            gemm_bias<<<grid_d, blk, 0, stream>>>(dec_emb, tok, 1, 0, E,
                                                  W_ih_d, b_ih_d, giE, H6, E);
            gemm_bias<<<grid_d, blk, 0, stream>>>(hh, nullptr, 0, 0, H2,
                                                  W_hh_d, b_hh_d, ghF, H6, H2);
            gru_gate<<<grid_dgate, blk, 0, stream>>>(giE, ghF, hh, H2);
            logits_argmax2<<<dim3(B / 2), blk, 0, stream>>>(hh, W_fc, b_fc, out, tok, t);
        }
    }
}